// Round 1
// baseline (1679.454 us; speedup 1.0000x reference)
//
#include <hip/hip_runtime.h>
#include <math.h>

#define T_SEQ 2048
#define HID   1024
#define NH    16
#define HD    64

// ---------------- GEMM: C[M,N] = A[M,K] @ W[N,K]^T (f32) ----------------
// 128x64 tile, 256 threads, each thread 8x4. K-major LDS staging so the
// per-kk fragment reads are contiguous float4s.
__global__ __launch_bounds__(256) void gemm_bt(
    const float* __restrict__ A,
    const float* __restrict__ W0, const float* __restrict__ W1, const float* __restrict__ W2,
    float* __restrict__ C0, float* __restrict__ C1, float* __restrict__ C2,
    int M, int N, int K)
{
    const float* W = blockIdx.z == 0 ? W0 : (blockIdx.z == 1 ? W1 : W2);
    float*       C = blockIdx.z == 0 ? C0 : (blockIdx.z == 1 ? C1 : C2);

    __shared__ float As[16][132];   // [kk][row], stride 132 keeps float4 align + bank spread
    __shared__ float Bs[16][68];    // [kk][col]

    const int bm = blockIdx.y * 128;
    const int bn = blockIdx.x * 64;
    const int tid = threadIdx.x;
    const int tx = tid & 15;        // -> n (4 cols)
    const int ty = tid >> 4;        // -> m (8 rows)

    float acc[8][4];
    #pragma unroll
    for (int m = 0; m < 8; ++m)
        #pragma unroll
        for (int n = 0; n < 4; ++n) acc[m][n] = 0.f;

    for (int k0 = 0; k0 < K; k0 += 16) {
        #pragma unroll
        for (int i = 0; i < 8; ++i) {
            int li = tid + i * 256;          // 0..2047
            int r = li >> 4, c = li & 15;
            As[c][r] = A[(size_t)(bm + r) * K + k0 + c];
        }
        #pragma unroll
        for (int i = 0; i < 4; ++i) {
            int li = tid + i * 256;          // 0..1023
            int r = li >> 4, c = li & 15;
            Bs[c][r] = W[(size_t)(bn + r) * K + k0 + c];
        }
        __syncthreads();
        #pragma unroll
        for (int kk = 0; kk < 16; ++kk) {
            float4 a0 = *reinterpret_cast<const float4*>(&As[kk][ty * 8]);
            float4 a1 = *reinterpret_cast<const float4*>(&As[kk][ty * 8 + 4]);
            float4 w  = *reinterpret_cast<const float4*>(&Bs[kk][tx * 4]);
            float am[8] = {a0.x, a0.y, a0.z, a0.w, a1.x, a1.y, a1.z, a1.w};
            float wn[4] = {w.x, w.y, w.z, w.w};
            #pragma unroll
            for (int m = 0; m < 8; ++m)
                #pragma unroll
                for (int n = 0; n < 4; ++n)
                    acc[m][n] += am[m] * wn[n];
        }
        __syncthreads();
    }
    #pragma unroll
    for (int m = 0; m < 8; ++m) {
        float4 o = make_float4(acc[m][0], acc[m][1], acc[m][2], acc[m][3]);
        *reinterpret_cast<float4*>(C + (size_t)(bm + ty * 8 + m) * N + bn + tx * 4) = o;
    }
}

// ---------------- f = log_sigmoid(hs @ Wf^T + bf), [T,NH] ----------------
__global__ __launch_bounds__(64) void fproj(const float* __restrict__ hs,
                                            const float* __restrict__ Wf,
                                            const float* __restrict__ bf,
                                            float* __restrict__ f)
{
    int t = blockIdx.x;
    int lane = threadIdx.x;
    const float* hrow = hs + (size_t)t * HID;
    for (int h = 0; h < NH; ++h) {
        const float* wrow = Wf + (size_t)h * HID;
        float s = 0.f;
        for (int j = lane; j < HID; j += 64) s += hrow[j] * wrow[j];
        #pragma unroll
        for (int off = 32; off > 0; off >>= 1) s += __shfl_down(s, off);
        if (lane == 0) {
            float x = s + bf[h];
            float ls = (x >= 0.f) ? -log1pf(expf(-x)) : (x - log1pf(expf(x)));
            f[t * NH + h] = ls;
        }
    }
}

// ---------------- fwd + reverse inclusive cumsum of f per head ----------------
__global__ __launch_bounds__(64) void cumsum_f(const float* __restrict__ f,
                                               float* __restrict__ gcf,
                                               float* __restrict__ gcb)
{
    int h = blockIdx.x;       // 16 heads
    int lane = threadIdx.x;   // 64
    float run = 0.f;
    for (int t0 = 0; t0 < T_SEQ; t0 += 64) {
        float x = f[(t0 + lane) * NH + h];
        #pragma unroll
        for (int off = 1; off < 64; off <<= 1) {
            float y = __shfl_up(x, off);
            if (lane >= off) x += y;
        }
        gcf[(t0 + lane) * NH + h] = run + x;
        run += __shfl(x, 63);
    }
    run = 0.f;
    for (int t0 = T_SEQ - 64; t0 >= 0; t0 -= 64) {
        int t = t0 + 63 - lane;
        float x = f[t * NH + h];
        #pragma unroll
        for (int off = 1; off < 64; off <<= 1) {
            float y = __shfl_up(x, off);
            if (lane >= off) x += y;
        }
        gcb[t * NH + h] = run + x;
        run += __shfl(x, 63);
    }
}

// ---------------- flash attention with forgetting decay ----------------
// dir=0: causal (k<=q) with gc=fwd cumsum.  dir=1: anti-causal (k>=q) with
// gc=reverse cumsum.  64 q-rows per block, 4 lanes per row each owning 16 dims.
__global__ __launch_bounds__(256) void attn_flash(
    const float* __restrict__ q, const float* __restrict__ k, const float* __restrict__ v,
    const float* __restrict__ gc, float* __restrict__ ocat, int dir)
{
    const int h  = blockIdx.y;
    const int qt = blockIdx.x;
    const int q0 = qt * 64;
    const int tid = threadIdx.x;
    const int r  = tid >> 2;      // q row in tile
    const int c4 = tid & 3;       // which 16-dim slice
    const int qi = q0 + r;

    __shared__ float4 Ks[64][16];
    __shared__ float4 Vs[64][16];
    __shared__ float  gks[64];

    float4 qreg[4];
    const float4* qrow = reinterpret_cast<const float4*>(q + (size_t)qi * HID + h * HD);
    #pragma unroll
    for (int m = 0; m < 4; ++m) {
        float4 t4 = qrow[c4 * 4 + m];
        qreg[m] = make_float4(t4.x * 0.125f, t4.y * 0.125f, t4.z * 0.125f, t4.w * 0.125f);
    }
    const float gq = gc[qi * NH + h];

    float mrun = -1e30f, lrun = 0.f;
    float4 acc[4];
    #pragma unroll
    for (int m = 0; m < 4; ++m) acc[m] = make_float4(0.f, 0.f, 0.f, 0.f);

    int kt0, kt1;
    if (dir == 0) { kt0 = 0;  kt1 = qt; }
    else          { kt0 = qt; kt1 = T_SEQ / 64 - 1; }

    for (int kt = kt0; kt <= kt1; ++kt) {
        const int k0 = kt * 64;
        __syncthreads();
        #pragma unroll
        for (int i = 0; i < 4; ++i) {
            int li = tid + i * 256;           // 0..1023 float4 slots
            int kr = li >> 4, kc = li & 15;
            Ks[kr][kc] = reinterpret_cast<const float4*>(k + (size_t)(k0 + kr) * HID + h * HD)[kc];
            Vs[kr][kc] = reinterpret_cast<const float4*>(v + (size_t)(k0 + kr) * HID + h * HD)[kc];
        }
        if (tid < 64) gks[tid] = gc[(k0 + tid) * NH + h];
        __syncthreads();

        for (int jj = 0; jj < 64; ++jj) {
            const int kj = k0 + jj;
            float s = 0.f;
            #pragma unroll
            for (int m = 0; m < 4; ++m) {
                float4 kk4 = Ks[jj][c4 * 4 + m];
                s += qreg[m].x * kk4.x + qreg[m].y * kk4.y
                   + qreg[m].z * kk4.z + qreg[m].w * kk4.w;
            }
            s += __shfl_xor(s, 1);
            s += __shfl_xor(s, 2);
            const bool valid = (dir == 0) ? (kj <= qi) : (kj >= qi);
            s = valid ? (s + gq - gks[jj]) : -1e30f;
            const float mn   = fmaxf(mrun, s);
            const float corr = __expf(mrun - mn);
            const float p    = valid ? __expf(s - mn) : 0.f;
            lrun = lrun * corr + p;
            #pragma unroll
            for (int m = 0; m < 4; ++m) {
                float4 vv = Vs[jj][c4 * 4 + m];
                acc[m].x = acc[m].x * corr + p * vv.x;
                acc[m].y = acc[m].y * corr + p * vv.y;
                acc[m].z = acc[m].z * corr + p * vv.z;
                acc[m].w = acc[m].w * corr + p * vv.w;
            }
            mrun = mn;
        }
    }

    const float inv = 1.f / lrun;
    float4* orow = reinterpret_cast<float4*>(ocat + (size_t)qi * (2 * HID) + dir * HID + h * HD + c4 * 16);
    #pragma unroll
    for (int m = 0; m < 4; ++m)
        orow[m] = make_float4(acc[m].x * inv, acc[m].y * inv, acc[m].z * inv, acc[m].w * inv);
}

// ---------------- launch ----------------
extern "C" void kernel_launch(void* const* d_in, const int* in_sizes, int n_in,
                              void* d_out, int out_size, void* d_ws, size_t ws_size,
                              hipStream_t stream)
{
    (void)in_sizes; (void)n_in; (void)out_size; (void)ws_size;
    const float* hs = (const float*)d_in[0];
    const float* Wq = (const float*)d_in[1];
    const float* Wk = (const float*)d_in[2];
    const float* Wv = (const float*)d_in[3];
    const float* Wf = (const float*)d_in[4];
    const float* bf = (const float*)d_in[5];
    const float* Wo = (const float*)d_in[6];
    float* out = (float*)d_out;

    float* ws   = (float*)d_ws;
    float* q    = ws;                          // 2048*1024
    float* k    = q    + (size_t)T_SEQ * HID;
    float* v    = k    + (size_t)T_SEQ * HID;
    float* f    = v    + (size_t)T_SEQ * HID;  // 2048*16
    float* gcf  = f    + (size_t)T_SEQ * NH;
    float* gcb  = gcf  + (size_t)T_SEQ * NH;
    float* ocat = gcb  + (size_t)T_SEQ * NH;   // 2048*2048

    // q,k,v projections (z-batched)
    gemm_bt<<<dim3(HID / 64, T_SEQ / 128, 3), 256, 0, stream>>>(
        hs, Wq, Wk, Wv, q, k, v, T_SEQ, HID, HID);
    // f projection + log_sigmoid
    fproj<<<T_SEQ, 64, 0, stream>>>(hs, Wf, bf, f);
    // cumsums
    cumsum_f<<<NH, 64, 0, stream>>>(f, gcf, gcb);
    // attention, both directions
    attn_flash<<<dim3(T_SEQ / 64, NH), 256, 0, stream>>>(q, k, v, gcf, ocat, 0);
    attn_flash<<<dim3(T_SEQ / 64, NH), 256, 0, stream>>>(q, k, v, gcb, ocat, 1);
    // output projection: out = ocat @ Wo^T
    gemm_bt<<<dim3(HID / 64, T_SEQ / 128, 1), 256, 0, stream>>>(
        ocat, Wo, nullptr, nullptr, out, nullptr, nullptr, T_SEQ, HID, 2 * HID);
}

// Round 2
// 547.408 us; speedup vs baseline: 3.0680x; 3.0680x over previous
//
#include <hip/hip_runtime.h>
#include <math.h>

#define T_SEQ 2048
#define HID   1024
#define NH    16
#define HD    64
#define NT    (T_SEQ / 64)

// ---------------- GEMM: C[M,N] = A[M,K] @ W[N,K]^T (f32) ----------------
__global__ __launch_bounds__(256) void gemm_bt(
    const float* __restrict__ A,
    const float* __restrict__ W0, const float* __restrict__ W1, const float* __restrict__ W2,
    float* __restrict__ C0, float* __restrict__ C1, float* __restrict__ C2,
    int M, int N, int K)
{
    const float* W = blockIdx.z == 0 ? W0 : (blockIdx.z == 1 ? W1 : W2);
    float*       C = blockIdx.z == 0 ? C0 : (blockIdx.z == 1 ? C1 : C2);

    __shared__ float As[16][132];
    __shared__ float Bs[16][68];

    const int bm = blockIdx.y * 128;
    const int bn = blockIdx.x * 64;
    const int tid = threadIdx.x;
    const int tx = tid & 15;
    const int ty = tid >> 4;

    float acc[8][4];
    #pragma unroll
    for (int m = 0; m < 8; ++m)
        #pragma unroll
        for (int n = 0; n < 4; ++n) acc[m][n] = 0.f;

    for (int k0 = 0; k0 < K; k0 += 16) {
        #pragma unroll
        for (int i = 0; i < 8; ++i) {
            int li = tid + i * 256;
            int r = li >> 4, c = li & 15;
            As[c][r] = A[(size_t)(bm + r) * K + k0 + c];
        }
        #pragma unroll
        for (int i = 0; i < 4; ++i) {
            int li = tid + i * 256;
            int r = li >> 4, c = li & 15;
            Bs[c][r] = W[(size_t)(bn + r) * K + k0 + c];
        }
        __syncthreads();
        #pragma unroll
        for (int kk = 0; kk < 16; ++kk) {
            float4 a0 = *reinterpret_cast<const float4*>(&As[kk][ty * 8]);
            float4 a1 = *reinterpret_cast<const float4*>(&As[kk][ty * 8 + 4]);
            float4 w  = *reinterpret_cast<const float4*>(&Bs[kk][tx * 4]);
            float am[8] = {a0.x, a0.y, a0.z, a0.w, a1.x, a1.y, a1.z, a1.w};
            float wn[4] = {w.x, w.y, w.z, w.w};
            #pragma unroll
            for (int m = 0; m < 8; ++m)
                #pragma unroll
                for (int n = 0; n < 4; ++n)
                    acc[m][n] += am[m] * wn[n];
        }
        __syncthreads();
    }
    #pragma unroll
    for (int m = 0; m < 8; ++m) {
        float4 o = make_float4(acc[m][0], acc[m][1], acc[m][2], acc[m][3]);
        *reinterpret_cast<float4*>(C + (size_t)(bm + ty * 8 + m) * N + bn + tx * 4) = o;
    }
}

// ---------------- f = log_sigmoid(hs @ Wf^T + bf), [T,NH] ----------------
__global__ __launch_bounds__(64) void fproj(const float* __restrict__ hs,
                                            const float* __restrict__ Wf,
                                            const float* __restrict__ bf,
                                            float* __restrict__ f)
{
    int t = blockIdx.x;
    int lane = threadIdx.x;
    const float* hrow = hs + (size_t)t * HID;
    for (int h = 0; h < NH; ++h) {
        const float* wrow = Wf + (size_t)h * HID;
        float s = 0.f;
        for (int j = lane; j < HID; j += 64) s += hrow[j] * wrow[j];
        #pragma unroll
        for (int off = 32; off > 0; off >>= 1) s += __shfl_down(s, off);
        if (lane == 0) {
            float x = s + bf[h];
            float ls = (x >= 0.f) ? -log1pf(expf(-x)) : (x - log1pf(expf(x)));
            f[t * NH + h] = ls;
        }
    }
}

// ---------------- fwd + reverse inclusive cumsum of f per head ----------------
__global__ __launch_bounds__(64) void cumsum_f(const float* __restrict__ f,
                                               float* __restrict__ gcf,
                                               float* __restrict__ gcb)
{
    int h = blockIdx.x;
    int lane = threadIdx.x;
    float run = 0.f;
    for (int t0 = 0; t0 < T_SEQ; t0 += 64) {
        float x = f[(t0 + lane) * NH + h];
        #pragma unroll
        for (int off = 1; off < 64; off <<= 1) {
            float y = __shfl_up(x, off);
            if (lane >= off) x += y;
        }
        gcf[(t0 + lane) * NH + h] = run + x;
        run += __shfl(x, 63);
    }
    run = 0.f;
    for (int t0 = T_SEQ - 64; t0 >= 0; t0 -= 64) {
        int t = t0 + 63 - lane;
        float x = f[t * NH + h];
        #pragma unroll
        for (int off = 1; off < 64; off <<= 1) {
            float y = __shfl_up(x, off);
            if (lane >= off) x += y;
        }
        gcb[t * NH + h] = run + x;
        run += __shfl(x, 63);
    }
}

// ---------------- per-head max ||k_row||_2 ----------------
__global__ __launch_bounds__(64) void knorms(const float* __restrict__ k,
                                             float* __restrict__ knmax)
{
    int h = blockIdx.x;
    int lane = threadIdx.x;
    float mx = 0.f;
    for (int t = lane; t < T_SEQ; t += 64) {
        const float4* kr = reinterpret_cast<const float4*>(k + (size_t)t * HID + h * HD);
        float s = 0.f;
        #pragma unroll
        for (int i = 0; i < 16; ++i) {
            float4 a = kr[i];
            s += a.x * a.x + a.y * a.y + a.z * a.z + a.w * a.w;
        }
        mx = fmaxf(mx, s);
    }
    #pragma unroll
    for (int off = 32; off > 0; off >>= 1) mx = fmaxf(mx, __shfl_xor(mx, off));
    if (lane == 0) knmax[h] = sqrtf(mx);
}

// ---------------- flash attention with forgetting decay + early exit ----------------
// Process k-tiles from the diagonal outward; break (block vote) when the
// rigorous score upper bound |q||k|max*scale + gq - gk_edge drops below
// mrun - 15 for every row (gc monotone => safe for all farther tiles).
__global__ __launch_bounds__(256) void attn_flash(
    const float* __restrict__ q, const float* __restrict__ k, const float* __restrict__ v,
    const float* __restrict__ gc, const float* __restrict__ knmax,
    float* __restrict__ ocat, int dir)
{
    const int h  = blockIdx.y;
    const int qt = blockIdx.x;
    const int q0 = qt * 64;
    const int tid = threadIdx.x;
    const int r  = tid >> 2;
    const int c4 = tid & 3;
    const int qi = q0 + r;

    __shared__ float4 Ks[64][16];
    __shared__ float4 Vs[64][16];
    __shared__ float  gks[64];

    float4 qreg[4];
    const float4* qrow = reinterpret_cast<const float4*>(q + (size_t)qi * HID + h * HD);
    #pragma unroll
    for (int m = 0; m < 4; ++m) {
        float4 t4 = qrow[c4 * 4 + m];
        qreg[m] = make_float4(t4.x * 0.125f, t4.y * 0.125f, t4.z * 0.125f, t4.w * 0.125f);
    }
    const float gq = gc[qi * NH + h];

    // |q_scaled| * max|k| upper bound on the qk term
    float qn2 = 0.f;
    #pragma unroll
    for (int m = 0; m < 4; ++m)
        qn2 += qreg[m].x * qreg[m].x + qreg[m].y * qreg[m].y
             + qreg[m].z * qreg[m].z + qreg[m].w * qreg[m].w;
    qn2 += __shfl_xor(qn2, 1);
    qn2 += __shfl_xor(qn2, 2);
    const float qbound = sqrtf(qn2) * knmax[h];

    float mrun = -1e30f, lrun = 0.f;
    float4 acc[4];
    #pragma unroll
    for (int m = 0; m < 4; ++m) acc[m] = make_float4(0.f, 0.f, 0.f, 0.f);

    const int step = (dir == 0) ? -1 : 1;
    for (int kt = qt; kt >= 0 && kt < NT; kt += step) {
        const int k0 = kt * 64;
        __syncthreads();
        #pragma unroll
        for (int i = 0; i < 4; ++i) {
            int li = tid + i * 256;
            int kr = li >> 4, kc = li & 15;
            Ks[kr][kc] = reinterpret_cast<const float4*>(k + (size_t)(k0 + kr) * HID + h * HD)[kc];
            Vs[kr][kc] = reinterpret_cast<const float4*>(v + (size_t)(k0 + kr) * HID + h * HD)[kc];
        }
        if (tid < 64) gks[tid] = gc[(k0 + tid) * NH + h];
        __syncthreads();

        for (int jj = 0; jj < 64; ++jj) {
            const int kj = k0 + jj;
            float s = 0.f;
            #pragma unroll
            for (int m = 0; m < 4; ++m) {
                float4 kk4 = Ks[jj][c4 * 4 + m];
                s += qreg[m].x * kk4.x + qreg[m].y * kk4.y
                   + qreg[m].z * kk4.z + qreg[m].w * kk4.w;
            }
            s += __shfl_xor(s, 1);
            s += __shfl_xor(s, 2);
            const bool valid = (dir == 0) ? (kj <= qi) : (kj >= qi);
            s = valid ? (s + gq - gks[jj]) : -1e30f;
            const float mn   = fmaxf(mrun, s);
            const float corr = __expf(mrun - mn);
            const float p    = valid ? __expf(s - mn) : 0.f;
            lrun = lrun * corr + p;
            #pragma unroll
            for (int m = 0; m < 4; ++m) {
                float4 vv = Vs[jj][c4 * 4 + m];
                acc[m].x = acc[m].x * corr + p * vv.x;
                acc[m].y = acc[m].y * corr + p * vv.y;
                acc[m].z = acc[m].z * corr + p * vv.z;
                acc[m].w = acc[m].w * corr + p * vv.w;
            }
            mrun = mn;
        }

        // early-exit vote for the next (more distant) tile
        const int nkt = kt + step;
        if (nkt >= 0 && nkt < NT) {
            const float gkedge = (dir == 0) ? gc[(nkt * 64 + 63) * NH + h]
                                            : gc[(nkt * 64) * NH + h];
            const int pred = (qbound + gq - gkedge) >= (mrun - 15.f);
            if (!__syncthreads_or(pred)) break;
        }
    }

    const float inv = 1.f / lrun;
    float4* orow = reinterpret_cast<float4*>(ocat + (size_t)qi * (2 * HID) + dir * HID + h * HD + c4 * 16);
    #pragma unroll
    for (int m = 0; m < 4; ++m)
        orow[m] = make_float4(acc[m].x * inv, acc[m].y * inv, acc[m].z * inv, acc[m].w * inv);
}

// ---------------- launch ----------------
extern "C" void kernel_launch(void* const* d_in, const int* in_sizes, int n_in,
                              void* d_out, int out_size, void* d_ws, size_t ws_size,
                              hipStream_t stream)
{
    (void)in_sizes; (void)n_in; (void)out_size; (void)ws_size;
    const float* hs = (const float*)d_in[0];
    const float* Wq = (const float*)d_in[1];
    const float* Wk = (const float*)d_in[2];
    const float* Wv = (const float*)d_in[3];
    const float* Wf = (const float*)d_in[4];
    const float* bf = (const float*)d_in[5];
    const float* Wo = (const float*)d_in[6];
    float* out = (float*)d_out;

    float* ws    = (float*)d_ws;
    float* q     = ws;
    float* k     = q     + (size_t)T_SEQ * HID;
    float* v     = k     + (size_t)T_SEQ * HID;
    float* f     = v     + (size_t)T_SEQ * HID;
    float* gcf   = f     + (size_t)T_SEQ * NH;
    float* gcb   = gcf   + (size_t)T_SEQ * NH;
    float* knmax = gcb   + (size_t)T_SEQ * NH;   // 16 floats
    float* ocat  = knmax + 64;                   // 2048*2048

    gemm_bt<<<dim3(HID / 64, T_SEQ / 128, 3), 256, 0, stream>>>(
        hs, Wq, Wk, Wv, q, k, v, T_SEQ, HID, HID);
    fproj<<<T_SEQ, 64, 0, stream>>>(hs, Wf, bf, f);
    cumsum_f<<<NH, 64, 0, stream>>>(f, gcf, gcb);
    knorms<<<NH, 64, 0, stream>>>(k, knmax);
    attn_flash<<<dim3(NT, NH), 256, 0, stream>>>(q, k, v, gcf, knmax, ocat, 0);
    attn_flash<<<dim3(NT, NH), 256, 0, stream>>>(q, k, v, gcb, knmax, ocat, 1);
    gemm_bt<<<dim3(HID / 64, T_SEQ / 128, 1), 256, 0, stream>>>(
        ocat, Wo, nullptr, nullptr, out, nullptr, nullptr, T_SEQ, HID, 2 * HID);
}

// Round 3
// 291.024 us; speedup vs baseline: 5.7708x; 1.8810x over previous
//
#include <hip/hip_runtime.h>
#include <math.h>

#define T_SEQ 2048
#define HID   1024
#define NH    16
#define HD    64
#define NT    (T_SEQ / 64)

typedef __attribute__((ext_vector_type(8))) __bf16 bf16x8;
typedef __attribute__((ext_vector_type(4))) float  f32x4;

#define GPTR(p) (const __attribute__((address_space(1))) void*)(p)
#define SPTR(p) (__attribute__((address_space(3))) void*)(p)

__device__ __forceinline__ unsigned short f2bf(float x) {
    unsigned u = __float_as_uint(x);
    u = (u + 0x7FFF + ((u >> 16) & 1)) >> 16;   // RNE
    return (unsigned short)u;
}

// ---------------- f32 -> bf16 conversion (5 segments) ----------------
__global__ __launch_bounds__(256) void f2bf_multi(
    const float* __restrict__ p0, const float* __restrict__ p1,
    const float* __restrict__ p2, const float* __restrict__ p3,
    const float* __restrict__ p4,
    unsigned short* o0, unsigned short* o1, unsigned short* o2,
    unsigned short* o3, unsigned short* o4,
    int n0, int n1, int n2, int n3, int n4)
{
    const float* in; unsigned short* out; int n;
    switch (blockIdx.y) {
        case 0: in = p0; out = o0; n = n0; break;
        case 1: in = p1; out = o1; n = n1; break;
        case 2: in = p2; out = o2; n = n2; break;
        case 3: in = p3; out = o3; n = n3; break;
        default: in = p4; out = o4; n = n4; break;
    }
    const int stride = gridDim.x * blockDim.x;
    for (int i = blockIdx.x * blockDim.x + threadIdx.x; i < n / 4; i += stride) {
        float4 v = reinterpret_cast<const float4*>(in)[i];
        ushort4 r;
        r.x = f2bf(v.x); r.y = f2bf(v.y); r.z = f2bf(v.z); r.w = f2bf(v.w);
        reinterpret_cast<ushort4*>(out)[i] = r;
    }
}

// ---------------- bf16 MFMA GEMM: C[M,N] = A[M,K] @ W[N,K]^T ----------------
// 128x128 tile, 4 waves (each 64x64), BK=64, global_load_lds width 16,
// XOR-swizzled LDS (linear dest + inverse-swizzled global source, rule #21).
__global__ __launch_bounds__(256) void gemm_mfma_bt(
    const unsigned short* __restrict__ A,
    const unsigned short* __restrict__ W0, const unsigned short* __restrict__ W1,
    const unsigned short* __restrict__ W2,
    float* __restrict__ C0, float* __restrict__ C1, float* __restrict__ C2,
    int M, int N, int K)
{
    const unsigned short* W = blockIdx.z == 0 ? W0 : (blockIdx.z == 1 ? W1 : W2);
    float*                C = blockIdx.z == 0 ? C0 : (blockIdx.z == 1 ? C1 : C2);

    __shared__ unsigned short Als[128 * 64];   // [row][k], row stride 128B, k-bytes XOR ((row&7)<<4)
    __shared__ unsigned short Bls[128 * 64];

    const int tid = threadIdx.x;
    const int w   = tid >> 6;        // wave 0..3
    const int l   = tid & 63;        // lane
    const int bm  = blockIdx.y * 128;
    const int bn  = blockIdx.x * 128;
    const int wm  = (w >> 1) * 64;   // wave row offset
    const int wn  = (w & 1) * 64;    // wave col offset

    f32x4 acc[4][4];
    #pragma unroll
    for (int m = 0; m < 4; ++m)
        #pragma unroll
        for (int n = 0; n < 4; ++n) acc[m][n] = (f32x4){0.f, 0.f, 0.f, 0.f};

    // per-lane constant pieces of the fragment addresses
    const int frow = l & 15;                  // fragment row within 16
    const int kgrp = (l >> 4) * 16;           // k-group byte offset (8 bf16)
    const int swz  = (l & 7) << 4;            // XOR swizzle, constant per lane

    const unsigned short* Ag = A + (size_t)bm * K;
    const unsigned short* Wg = W + (size_t)bn * K;

    for (int k0 = 0; k0 < K; k0 += 64) {
        __syncthreads();   // previous iter's reads done before overwrite
        #pragma unroll
        for (int j = 0; j < 4; ++j) {
            const int idxb = j * 4096 + tid * 16;          // linear byte in tile
            const int row  = idxb >> 7;                    // /128B per row
            const int kb   = idxb & 127;
            const int col  = (kb ^ ((row & 7) << 4)) >> 1; // inverse-swizzled source col
            const int ldsb = j * 4096 + w * 1024;          // wave-uniform dest base
            __builtin_amdgcn_global_load_lds(
                GPTR(Ag + (size_t)row * K + k0 + col),
                SPTR(Als + (ldsb >> 1)), 16, 0, 0);
            __builtin_amdgcn_global_load_lds(
                GPTR(Wg + (size_t)row * K + k0 + col),
                SPTR(Bls + (ldsb >> 1)), 16, 0, 0);
        }
        __syncthreads();   // staging complete (vmcnt drained by barrier)

        #pragma unroll
        for (int ks = 0; ks < 2; ++ks) {
            bf16x8 af[4], bfr[4];
            #pragma unroll
            for (int m = 0; m < 4; ++m) {
                const int off = (wm + m * 16 + frow) * 128 + ((ks * 64 + kgrp) ^ swz);
                af[m] = *reinterpret_cast<const bf16x8*>((const char*)Als + off);
            }
            #pragma unroll
            for (int n = 0; n < 4; ++n) {
                const int off = (wn + n * 16 + frow) * 128 + ((ks * 64 + kgrp) ^ swz);
                bfr[n] = *reinterpret_cast<const bf16x8*>((const char*)Bls + off);
            }
            #pragma unroll
            for (int m = 0; m < 4; ++m)
                #pragma unroll
                for (int n = 0; n < 4; ++n)
                    acc[m][n] = __builtin_amdgcn_mfma_f32_16x16x32_bf16(
                        af[m], bfr[n], acc[m][n], 0, 0, 0);
        }
    }

    // C/D layout: col = lane&15, row = (lane>>4)*4 + reg
    const int r0 = (l >> 4) * 4;
    const int cc = l & 15;
    #pragma unroll
    for (int m = 0; m < 4; ++m)
        #pragma unroll
        for (int n = 0; n < 4; ++n) {
            float* cp = C + (size_t)(bm + wm + m * 16 + r0) * N + bn + wn + n * 16 + cc;
            #pragma unroll
            for (int r = 0; r < 4; ++r) cp[(size_t)r * N] = acc[m][n][r];
        }
}

// ---------------- f = log_sigmoid(hs @ Wf^T + bf), [T,NH] ----------------
__global__ __launch_bounds__(64) void fproj(const float* __restrict__ hs,
                                            const float* __restrict__ Wf,
                                            const float* __restrict__ bf,
                                            float* __restrict__ f)
{
    int t = blockIdx.x;
    int lane = threadIdx.x;
    const float* hrow = hs + (size_t)t * HID;
    for (int h = 0; h < NH; ++h) {
        const float* wrow = Wf + (size_t)h * HID;
        float s = 0.f;
        for (int j = lane; j < HID; j += 64) s += hrow[j] * wrow[j];
        #pragma unroll
        for (int off = 32; off > 0; off >>= 1) s += __shfl_down(s, off);
        if (lane == 0) {
            float x = s + bf[h];
            float ls = (x >= 0.f) ? -log1pf(expf(-x)) : (x - log1pf(expf(x)));
            f[t * NH + h] = ls;
        }
    }
}

// ---------------- fwd + reverse inclusive cumsum of f per head ----------------
__global__ __launch_bounds__(64) void cumsum_f(const float* __restrict__ f,
                                               float* __restrict__ gcf,
                                               float* __restrict__ gcb)
{
    int h = blockIdx.x;
    int lane = threadIdx.x;
    float run = 0.f;
    for (int t0 = 0; t0 < T_SEQ; t0 += 64) {
        float x = f[(t0 + lane) * NH + h];
        #pragma unroll
        for (int off = 1; off < 64; off <<= 1) {
            float y = __shfl_up(x, off);
            if (lane >= off) x += y;
        }
        gcf[(t0 + lane) * NH + h] = run + x;
        run += __shfl(x, 63);
    }
    run = 0.f;
    for (int t0 = T_SEQ - 64; t0 >= 0; t0 -= 64) {
        int t = t0 + 63 - lane;
        float x = f[t * NH + h];
        #pragma unroll
        for (int off = 1; off < 64; off <<= 1) {
            float y = __shfl_up(x, off);
            if (lane >= off) x += y;
        }
        gcb[t * NH + h] = run + x;
        run += __shfl(x, 63);
    }
}

// ---------------- per-head max ||k_row||_2 ----------------
__global__ __launch_bounds__(64) void knorms(const float* __restrict__ k,
                                             float* __restrict__ knmax)
{
    int h = blockIdx.x;
    int lane = threadIdx.x;
    float mx = 0.f;
    for (int t = lane; t < T_SEQ; t += 64) {
        const float4* kr = reinterpret_cast<const float4*>(k + (size_t)t * HID + h * HD);
        float s = 0.f;
        #pragma unroll
        for (int i = 0; i < 16; ++i) {
            float4 a = kr[i];
            s += a.x * a.x + a.y * a.y + a.z * a.z + a.w * a.w;
        }
        mx = fmaxf(mx, s);
    }
    #pragma unroll
    for (int off = 32; off > 0; off >>= 1) mx = fmaxf(mx, __shfl_xor(mx, off));
    if (lane == 0) knmax[h] = sqrtf(mx);
}

// ---------------- flash attention with forgetting decay + early exit ----------------
__global__ __launch_bounds__(256) void attn_flash(
    const float* __restrict__ q, const float* __restrict__ k, const float* __restrict__ v,
    const float* __restrict__ gc, const float* __restrict__ knmax,
    unsigned short* __restrict__ ocat, int dir)
{
    const int h  = blockIdx.y;
    const int qt = blockIdx.x;
    const int q0 = qt * 64;
    const int tid = threadIdx.x;
    const int r  = tid >> 2;
    const int c4 = tid & 3;
    const int qi = q0 + r;

    __shared__ float4 Ks[64][16];
    __shared__ float4 Vs[64][16];
    __shared__ float  gks[64];

    float4 qreg[4];
    const float4* qrow = reinterpret_cast<const float4*>(q + (size_t)qi * HID + h * HD);
    #pragma unroll
    for (int m = 0; m < 4; ++m) {
        float4 t4 = qrow[c4 * 4 + m];
        qreg[m] = make_float4(t4.x * 0.125f, t4.y * 0.125f, t4.z * 0.125f, t4.w * 0.125f);
    }
    const float gq = gc[qi * NH + h];

    float qn2 = 0.f;
    #pragma unroll
    for (int m = 0; m < 4; ++m)
        qn2 += qreg[m].x * qreg[m].x + qreg[m].y * qreg[m].y
             + qreg[m].z * qreg[m].z + qreg[m].w * qreg[m].w;
    qn2 += __shfl_xor(qn2, 1);
    qn2 += __shfl_xor(qn2, 2);
    const float qbound = sqrtf(qn2) * knmax[h];

    float mrun = -1e30f, lrun = 0.f;
    float4 acc[4];
    #pragma unroll
    for (int m = 0; m < 4; ++m) acc[m] = make_float4(0.f, 0.f, 0.f, 0.f);

    const int step = (dir == 0) ? -1 : 1;
    for (int kt = qt; kt >= 0 && kt < NT; kt += step) {
        const int k0 = kt * 64;
        __syncthreads();
        #pragma unroll
        for (int i = 0; i < 4; ++i) {
            int li = tid + i * 256;
            int kr = li >> 4, kc = li & 15;
            Ks[kr][kc] = reinterpret_cast<const float4*>(k + (size_t)(k0 + kr) * HID + h * HD)[kc];
            Vs[kr][kc] = reinterpret_cast<const float4*>(v + (size_t)(k0 + kr) * HID + h * HD)[kc];
        }
        if (tid < 64) gks[tid] = gc[(k0 + tid) * NH + h];
        __syncthreads();

        for (int jj = 0; jj < 64; ++jj) {
            const int kj = k0 + jj;
            float s = 0.f;
            #pragma unroll
            for (int m = 0; m < 4; ++m) {
                float4 kk4 = Ks[jj][c4 * 4 + m];
                s += qreg[m].x * kk4.x + qreg[m].y * kk4.y
                   + qreg[m].z * kk4.z + qreg[m].w * kk4.w;
            }
            s += __shfl_xor(s, 1);
            s += __shfl_xor(s, 2);
            const bool valid = (dir == 0) ? (kj <= qi) : (kj >= qi);
            s = valid ? (s + gq - gks[jj]) : -1e30f;
            const float mn   = fmaxf(mrun, s);
            const float corr = __expf(mrun - mn);
            const float p    = valid ? __expf(s - mn) : 0.f;
            lrun = lrun * corr + p;
            #pragma unroll
            for (int m = 0; m < 4; ++m) {
                float4 vv = Vs[jj][c4 * 4 + m];
                acc[m].x = acc[m].x * corr + p * vv.x;
                acc[m].y = acc[m].y * corr + p * vv.y;
                acc[m].z = acc[m].z * corr + p * vv.z;
                acc[m].w = acc[m].w * corr + p * vv.w;
            }
            mrun = mn;
        }

        const int nkt = kt + step;
        if (nkt >= 0 && nkt < NT) {
            const float gkedge = (dir == 0) ? gc[(nkt * 64 + 63) * NH + h]
                                            : gc[(nkt * 64) * NH + h];
            const int pred = (qbound + gq - gkedge) >= (mrun - 15.f);
            if (!__syncthreads_or(pred)) break;
        }
    }

    const float inv = 1.f / lrun;
    unsigned short* orow = ocat + (size_t)qi * (2 * HID) + dir * HID + h * HD + c4 * 16;
    #pragma unroll
    for (int m = 0; m < 4; ++m) {
        ushort4 o;
        o.x = f2bf(acc[m].x * inv); o.y = f2bf(acc[m].y * inv);
        o.z = f2bf(acc[m].z * inv); o.w = f2bf(acc[m].w * inv);
        reinterpret_cast<ushort4*>(orow)[m] = o;
    }
}

// ---------------- launch ----------------
extern "C" void kernel_launch(void* const* d_in, const int* in_sizes, int n_in,
                              void* d_out, int out_size, void* d_ws, size_t ws_size,
                              hipStream_t stream)
{
    (void)in_sizes; (void)n_in; (void)out_size; (void)ws_size;
    const float* hs = (const float*)d_in[0];
    const float* Wq = (const float*)d_in[1];
    const float* Wk = (const float*)d_in[2];
    const float* Wv = (const float*)d_in[3];
    const float* Wf = (const float*)d_in[4];
    const float* bf = (const float*)d_in[5];
    const float* Wo = (const float*)d_in[6];
    float* out = (float*)d_out;

    float* ws    = (float*)d_ws;
    float* q     = ws;                               // [T,HID] f32
    float* k     = q     + (size_t)T_SEQ * HID;
    float* v     = k     + (size_t)T_SEQ * HID;
    float* f     = v     + (size_t)T_SEQ * HID;      // [T,NH]
    float* gcf   = f     + (size_t)T_SEQ * NH;
    float* gcb   = gcf   + (size_t)T_SEQ * NH;
    float* knmax = gcb   + (size_t)T_SEQ * NH;       // 64 floats
    unsigned short* hsb  = (unsigned short*)(knmax + 64);
    unsigned short* wqb  = hsb + (size_t)T_SEQ * HID;
    unsigned short* wkb  = wqb + (size_t)HID * HID;
    unsigned short* wvb  = wkb + (size_t)HID * HID;
    unsigned short* wob  = wvb + (size_t)HID * HID;
    unsigned short* ocat = wob + (size_t)HID * 2 * HID;   // [T, 2*HID] bf16

    // f32 -> bf16: hs, Wq, Wk, Wv, Wo
    f2bf_multi<<<dim3(256, 5), 256, 0, stream>>>(
        hs, Wq, Wk, Wv, Wo, hsb, wqb, wkb, wvb, wob,
        T_SEQ * HID, HID * HID, HID * HID, HID * HID, HID * 2 * HID);

    // q,k,v projections (bf16 MFMA, z-batched)
    gemm_mfma_bt<<<dim3(HID / 128, T_SEQ / 128, 3), 256, 0, stream>>>(
        hsb, wqb, wkb, wvb, q, k, v, T_SEQ, HID, HID);

    fproj<<<T_SEQ, 64, 0, stream>>>(hs, Wf, bf, f);
    cumsum_f<<<NH, 64, 0, stream>>>(f, gcf, gcb);
    knorms<<<NH, 64, 0, stream>>>(k, knmax);

    attn_flash<<<dim3(NT, NH), 256, 0, stream>>>(q, k, v, gcf, knmax, ocat, 0);
    attn_flash<<<dim3(NT, NH), 256, 0, stream>>>(q, k, v, gcb, knmax, ocat, 1);

    // out = ocat @ Wo^T (bf16 MFMA)
    gemm_mfma_bt<<<dim3(HID / 128, T_SEQ / 128, 1), 256, 0, stream>>>(
        ocat, wob, nullptr, nullptr, out, nullptr, nullptr, T_SEQ, HID, 2 * HID);
}

// Round 4
// 174.558 us; speedup vs baseline: 9.6212x; 1.6672x over previous
//
#include <hip/hip_runtime.h>
#include <math.h>

#define T_SEQ 2048
#define HID   1024
#define NH    16
#define HD    64
#define NT    (T_SEQ / 64)

typedef __attribute__((ext_vector_type(8))) __bf16 bf16x8;
typedef __attribute__((ext_vector_type(4))) float  f32x4;

#define GPTR(p) (const __attribute__((address_space(1))) void*)(p)
#define SPTR(p) (__attribute__((address_space(3))) void*)(p)

__device__ __forceinline__ unsigned short f2bf(float x) {
    unsigned u = __float_as_uint(x);
    u = (u + 0x7FFF + ((u >> 16) & 1)) >> 16;   // RNE
    return (unsigned short)u;
}

// ---------------- f32 -> bf16 conversion (5 segments) ----------------
__global__ __launch_bounds__(256) void f2bf_multi(
    const float* __restrict__ p0, const float* __restrict__ p1,
    const float* __restrict__ p2, const float* __restrict__ p3,
    const float* __restrict__ p4,
    unsigned short* o0, unsigned short* o1, unsigned short* o2,
    unsigned short* o3, unsigned short* o4,
    int n0, int n1, int n2, int n3, int n4)
{
    const float* in; unsigned short* out; int n;
    switch (blockIdx.y) {
        case 0: in = p0; out = o0; n = n0; break;
        case 1: in = p1; out = o1; n = n1; break;
        case 2: in = p2; out = o2; n = n2; break;
        case 3: in = p3; out = o3; n = n3; break;
        default: in = p4; out = o4; n = n4; break;
    }
    const int stride = gridDim.x * blockDim.x;
    for (int i = blockIdx.x * blockDim.x + threadIdx.x; i < n / 4; i += stride) {
        float4 v = reinterpret_cast<const float4*>(in)[i];
        ushort4 r;
        r.x = f2bf(v.x); r.y = f2bf(v.y); r.z = f2bf(v.z); r.w = f2bf(v.w);
        reinterpret_cast<ushort4*>(out)[i] = r;
    }
}

// ---------------- bf16 MFMA GEMM: C[M,N] = A[M,K] @ W[N,K]^T ----------------
__global__ __launch_bounds__(256) void gemm_mfma_bt(
    const unsigned short* __restrict__ A,
    const unsigned short* __restrict__ W0, const unsigned short* __restrict__ W1,
    const unsigned short* __restrict__ W2,
    float* __restrict__ C0, float* __restrict__ C1, float* __restrict__ C2,
    int M, int N, int K)
{
    const unsigned short* W = blockIdx.z == 0 ? W0 : (blockIdx.z == 1 ? W1 : W2);
    float*                C = blockIdx.z == 0 ? C0 : (blockIdx.z == 1 ? C1 : C2);

    __shared__ unsigned short Als[128 * 64];
    __shared__ unsigned short Bls[128 * 64];

    const int tid = threadIdx.x;
    const int w   = tid >> 6;
    const int l   = tid & 63;
    const int bm  = blockIdx.y * 128;
    const int bn  = blockIdx.x * 128;
    const int wm  = (w >> 1) * 64;
    const int wn  = (w & 1) * 64;

    f32x4 acc[4][4];
    #pragma unroll
    for (int m = 0; m < 4; ++m)
        #pragma unroll
        for (int n = 0; n < 4; ++n) acc[m][n] = (f32x4){0.f, 0.f, 0.f, 0.f};

    const int frow = l & 15;
    const int kgrp = (l >> 4) * 16;
    const int swz  = (l & 7) << 4;

    const unsigned short* Ag = A + (size_t)bm * K;
    const unsigned short* Wg = W + (size_t)bn * K;

    for (int k0 = 0; k0 < K; k0 += 64) {
        __syncthreads();
        #pragma unroll
        for (int j = 0; j < 4; ++j) {
            const int idxb = j * 4096 + tid * 16;
            const int row  = idxb >> 7;
            const int kb   = idxb & 127;
            const int col  = (kb ^ ((row & 7) << 4)) >> 1;
            const int ldsb = j * 4096 + w * 1024;
            __builtin_amdgcn_global_load_lds(
                GPTR(Ag + (size_t)row * K + k0 + col),
                SPTR(Als + (ldsb >> 1)), 16, 0, 0);
            __builtin_amdgcn_global_load_lds(
                GPTR(Wg + (size_t)row * K + k0 + col),
                SPTR(Bls + (ldsb >> 1)), 16, 0, 0);
        }
        __syncthreads();

        #pragma unroll
        for (int ks = 0; ks < 2; ++ks) {
            bf16x8 af[4], bfr[4];
            #pragma unroll
            for (int m = 0; m < 4; ++m) {
                const int off = (wm + m * 16 + frow) * 128 + ((ks * 64 + kgrp) ^ swz);
                af[m] = *reinterpret_cast<const bf16x8*>((const char*)Als + off);
            }
            #pragma unroll
            for (int n = 0; n < 4; ++n) {
                const int off = (wn + n * 16 + frow) * 128 + ((ks * 64 + kgrp) ^ swz);
                bfr[n] = *reinterpret_cast<const bf16x8*>((const char*)Bls + off);
            }
            #pragma unroll
            for (int m = 0; m < 4; ++m)
                #pragma unroll
                for (int n = 0; n < 4; ++n)
                    acc[m][n] = __builtin_amdgcn_mfma_f32_16x16x32_bf16(
                        af[m], bfr[n], acc[m][n], 0, 0, 0);
        }
    }

    const int r0 = (l >> 4) * 4;
    const int cc = l & 15;
    #pragma unroll
    for (int m = 0; m < 4; ++m)
        #pragma unroll
        for (int n = 0; n < 4; ++n) {
            float* cp = C + (size_t)(bm + wm + m * 16 + r0) * N + bn + wn + n * 16 + cc;
            #pragma unroll
            for (int r = 0; r < 4; ++r) cp[(size_t)r * N] = acc[m][n][r];
        }
}

// ---------------- f = log_sigmoid(hs @ Wf^T + bf), [T,NH] ----------------
// 256 threads/block: 16 threads per head, float4 loads, 4-step xor reduce.
__global__ __launch_bounds__(256) void fproj(const float* __restrict__ hs,
                                             const float* __restrict__ Wf,
                                             const float* __restrict__ bf,
                                             float* __restrict__ f)
{
    const int t  = blockIdx.x;
    const int h  = threadIdx.x >> 4;
    const int sl = threadIdx.x & 15;
    const float4* hrow = reinterpret_cast<const float4*>(hs + (size_t)t * HID);
    const float4* wrow = reinterpret_cast<const float4*>(Wf + (size_t)h * HID);
    float s = 0.f;
    #pragma unroll
    for (int i = 0; i < 16; ++i) {
        float4 a = hrow[sl + i * 16];
        float4 b = wrow[sl + i * 16];
        s += a.x * b.x + a.y * b.y + a.z * b.z + a.w * b.w;
    }
    s += __shfl_xor(s, 1);
    s += __shfl_xor(s, 2);
    s += __shfl_xor(s, 4);
    s += __shfl_xor(s, 8);
    if (sl == 0) {
        float x = s + bf[h];
        f[t * NH + h] = (x >= 0.f) ? -log1pf(expf(-x)) : (x - log1pf(expf(x)));
    }
}

// ---------------- fwd/bwd inclusive cumsum, 4 waves x 512-elem segments ----------------
// grid (NH, 2): blockIdx.y = 0 fwd, 1 bwd. Logical position p scans the
// (possibly reversed) sequence; wave wv owns p in [wv*512, wv*512+512).
__global__ __launch_bounds__(256) void cumsum_f(const float* __restrict__ f,
                                                float* __restrict__ gcf,
                                                float* __restrict__ gcb)
{
    const int h   = blockIdx.x;
    const int rev = blockIdx.y;
    float* out = rev ? gcb : gcf;
    const int wv   = threadIdx.x >> 6;
    const int lane = threadIdx.x & 63;

    __shared__ float wtot[4];

    float vals[8];
    float run = 0.f;
    #pragma unroll
    for (int c = 0; c < 8; ++c) {
        const int p = wv * 512 + c * 64 + lane;
        const int t = rev ? (T_SEQ - 1 - p) : p;
        float x = f[t * NH + h];
        #pragma unroll
        for (int off = 1; off < 64; off <<= 1) {
            float y = __shfl_up(x, off);
            if (lane >= off) x += y;
        }
        vals[c] = run + x;
        run += __shfl(x, 63);
    }
    if (lane == 0) wtot[wv] = run;
    __syncthreads();
    float prefix = 0.f;
    #pragma unroll
    for (int i = 0; i < 4; ++i) prefix += (i < wv) ? wtot[i] : 0.f;
    #pragma unroll
    for (int c = 0; c < 8; ++c) {
        const int p = wv * 512 + c * 64 + lane;
        const int t = rev ? (T_SEQ - 1 - p) : p;
        out[t * NH + h] = vals[c] + prefix;
    }
}

// ---------------- per-head max ||k_row||_2 (256 threads) ----------------
__global__ __launch_bounds__(256) void knorms(const float* __restrict__ k,
                                              float* __restrict__ knmax)
{
    const int h   = blockIdx.x;
    const int tid = threadIdx.x;
    const int wv  = tid >> 6;
    const int lane = tid & 63;
    __shared__ float wmax[4];
    float mx = 0.f;
    for (int t = tid; t < T_SEQ; t += 256) {
        const float4* kr = reinterpret_cast<const float4*>(k + (size_t)t * HID + h * HD);
        float s = 0.f;
        #pragma unroll
        for (int i = 0; i < 16; ++i) {
            float4 a = kr[i];
            s += a.x * a.x + a.y * a.y + a.z * a.z + a.w * a.w;
        }
        mx = fmaxf(mx, s);
    }
    #pragma unroll
    for (int off = 32; off > 0; off >>= 1) mx = fmaxf(mx, __shfl_xor(mx, off));
    if (lane == 0) wmax[wv] = mx;
    __syncthreads();
    if (tid == 0) {
        float m = fmaxf(fmaxf(wmax[0], wmax[1]), fmaxf(wmax[2], wmax[3]));
        knmax[h] = sqrtf(m);
    }
}

// ---------------- flash attention, both dirs in one launch (blockIdx.z) ----------------
__global__ __launch_bounds__(256) void attn_flash(
    const float* __restrict__ q, const float* __restrict__ k, const float* __restrict__ v,
    const float* __restrict__ gcf, const float* __restrict__ gcb,
    const float* __restrict__ knmax,
    unsigned short* __restrict__ ocat)
{
    const int dir = blockIdx.z;
    const float* gc = dir ? gcb : gcf;
    const int h  = blockIdx.y;
    const int qt = blockIdx.x;
    const int q0 = qt * 64;
    const int tid = threadIdx.x;
    const int r  = tid >> 2;
    const int c4 = tid & 3;
    const int qi = q0 + r;

    __shared__ float4 Ks[64][16];
    __shared__ float4 Vs[64][16];
    __shared__ float  gks[64];

    float4 qreg[4];
    const float4* qrow = reinterpret_cast<const float4*>(q + (size_t)qi * HID + h * HD);
    #pragma unroll
    for (int m = 0; m < 4; ++m) {
        float4 t4 = qrow[c4 * 4 + m];
        qreg[m] = make_float4(t4.x * 0.125f, t4.y * 0.125f, t4.z * 0.125f, t4.w * 0.125f);
    }
    const float gq = gc[qi * NH + h];

    float qn2 = 0.f;
    #pragma unroll
    for (int m = 0; m < 4; ++m)
        qn2 += qreg[m].x * qreg[m].x + qreg[m].y * qreg[m].y
             + qreg[m].z * qreg[m].z + qreg[m].w * qreg[m].w;
    qn2 += __shfl_xor(qn2, 1);
    qn2 += __shfl_xor(qn2, 2);
    const float qbound = sqrtf(qn2) * knmax[h];

    float mrun = -1e30f, lrun = 0.f;
    float4 acc[4];
    #pragma unroll
    for (int m = 0; m < 4; ++m) acc[m] = make_float4(0.f, 0.f, 0.f, 0.f);

    const int step = (dir == 0) ? -1 : 1;
    for (int kt = qt; kt >= 0 && kt < NT; kt += step) {
        const int k0 = kt * 64;
        __syncthreads();
        #pragma unroll
        for (int i = 0; i < 4; ++i) {
            int li = tid + i * 256;
            int kr = li >> 4, kc = li & 15;
            Ks[kr][kc] = reinterpret_cast<const float4*>(k + (size_t)(k0 + kr) * HID + h * HD)[kc];
            Vs[kr][kc] = reinterpret_cast<const float4*>(v + (size_t)(k0 + kr) * HID + h * HD)[kc];
        }
        if (tid < 64) gks[tid] = gc[(k0 + tid) * NH + h];
        __syncthreads();

        for (int jj = 0; jj < 64; ++jj) {
            const int kj = k0 + jj;
            float s = 0.f;
            #pragma unroll
            for (int m = 0; m < 4; ++m) {
                float4 kk4 = Ks[jj][c4 * 4 + m];
                s += qreg[m].x * kk4.x + qreg[m].y * kk4.y
                   + qreg[m].z * kk4.z + qreg[m].w * kk4.w;
            }
            s += __shfl_xor(s, 1);
            s += __shfl_xor(s, 2);
            const bool valid = (dir == 0) ? (kj <= qi) : (kj >= qi);
            s = valid ? (s + gq - gks[jj]) : -1e30f;
            const float mn   = fmaxf(mrun, s);
            const float corr = __expf(mrun - mn);
            const float p    = valid ? __expf(s - mn) : 0.f;
            lrun = lrun * corr + p;
            #pragma unroll
            for (int m = 0; m < 4; ++m) {
                float4 vv = Vs[jj][c4 * 4 + m];
                acc[m].x = acc[m].x * corr + p * vv.x;
                acc[m].y = acc[m].y * corr + p * vv.y;
                acc[m].z = acc[m].z * corr + p * vv.z;
                acc[m].w = acc[m].w * corr + p * vv.w;
            }
            mrun = mn;
        }

        const int nkt = kt + step;
        if (nkt >= 0 && nkt < NT) {
            const float gkedge = (dir == 0) ? gc[(nkt * 64 + 63) * NH + h]
                                            : gc[(nkt * 64) * NH + h];
            const int pred = (qbound + gq - gkedge) >= (mrun - 15.f);
            if (!__syncthreads_or(pred)) break;
        }
    }

    const float inv = 1.f / lrun;
    unsigned short* orow = ocat + (size_t)qi * (2 * HID) + dir * HID + h * HD + c4 * 16;
    #pragma unroll
    for (int m = 0; m < 4; ++m) {
        ushort4 o;
        o.x = f2bf(acc[m].x * inv); o.y = f2bf(acc[m].y * inv);
        o.z = f2bf(acc[m].z * inv); o.w = f2bf(acc[m].w * inv);
        reinterpret_cast<ushort4*>(orow)[m] = o;
    }
}

// ---------------- launch ----------------
extern "C" void kernel_launch(void* const* d_in, const int* in_sizes, int n_in,
                              void* d_out, int out_size, void* d_ws, size_t ws_size,
                              hipStream_t stream)
{
    (void)in_sizes; (void)n_in; (void)out_size; (void)ws_size;
    const float* hs = (const float*)d_in[0];
    const float* Wq = (const float*)d_in[1];
    const float* Wk = (const float*)d_in[2];
    const float* Wv = (const float*)d_in[3];
    const float* Wf = (const float*)d_in[4];
    const float* bf = (const float*)d_in[5];
    const float* Wo = (const float*)d_in[6];
    float* out = (float*)d_out;

    float* ws    = (float*)d_ws;
    float* q     = ws;
    float* k     = q     + (size_t)T_SEQ * HID;
    float* v     = k     + (size_t)T_SEQ * HID;
    float* f     = v     + (size_t)T_SEQ * HID;
    float* gcf   = f     + (size_t)T_SEQ * NH;
    float* gcb   = gcf   + (size_t)T_SEQ * NH;
    float* knmax = gcb   + (size_t)T_SEQ * NH;
    unsigned short* hsb  = (unsigned short*)(knmax + 64);
    unsigned short* wqb  = hsb + (size_t)T_SEQ * HID;
    unsigned short* wkb  = wqb + (size_t)HID * HID;
    unsigned short* wvb  = wkb + (size_t)HID * HID;
    unsigned short* wob  = wvb + (size_t)HID * HID;
    unsigned short* ocat = wob + (size_t)HID * 2 * HID;

    f2bf_multi<<<dim3(256, 5), 256, 0, stream>>>(
        hs, Wq, Wk, Wv, Wo, hsb, wqb, wkb, wvb, wob,
        T_SEQ * HID, HID * HID, HID * HID, HID * HID, HID * 2 * HID);

    gemm_mfma_bt<<<dim3(HID / 128, T_SEQ / 128, 3), 256, 0, stream>>>(
        hsb, wqb, wkb, wvb, q, k, v, T_SEQ, HID, HID);

    fproj<<<T_SEQ, 256, 0, stream>>>(hs, Wf, bf, f);
    cumsum_f<<<dim3(NH, 2), 256, 0, stream>>>(f, gcf, gcb);
    knorms<<<NH, 256, 0, stream>>>(k, knmax);

    attn_flash<<<dim3(NT, NH, 2), 256, 0, stream>>>(q, k, v, gcf, gcb, knmax, ocat);

    gemm_mfma_bt<<<dim3(HID / 128, T_SEQ / 128, 1), 256, 0, stream>>>(
        ocat, wob, nullptr, nullptr, out, nullptr, nullptr, T_SEQ, HID, 2 * HID);
}

// Round 5
// 132.809 us; speedup vs baseline: 12.6456x; 1.3144x over previous
//
#include <hip/hip_runtime.h>
#include <math.h>

#define T_SEQ 2048
#define HID   1024
#define NH    16
#define HD    64
#define NT    (T_SEQ / 64)

typedef __attribute__((ext_vector_type(8))) __bf16 bf16x8;
typedef __attribute__((ext_vector_type(4))) float  f32x4;
typedef __attribute__((ext_vector_type(8))) unsigned short u16x8;

#define GPTR(p) (const __attribute__((address_space(1))) void*)(p)
#define SPTR(p) (__attribute__((address_space(3))) void*)(p)

__device__ __forceinline__ unsigned short f2bf(float x) {
    unsigned u = __float_as_uint(x);
    u = (u + 0x7FFF + ((u >> 16) & 1)) >> 16;   // RNE
    return (unsigned short)u;
}

// ---------------- f32 -> bf16 conversion (5 segments) ----------------
__global__ __launch_bounds__(256) void f2bf_multi(
    const float* __restrict__ p0, const float* __restrict__ p1,
    const float* __restrict__ p2, const float* __restrict__ p3,
    const float* __restrict__ p4,
    unsigned short* o0, unsigned short* o1, unsigned short* o2,
    unsigned short* o3, unsigned short* o4,
    int n0, int n1, int n2, int n3, int n4)
{
    const float* in; unsigned short* out; int n;
    switch (blockIdx.y) {
        case 0: in = p0; out = o0; n = n0; break;
        case 1: in = p1; out = o1; n = n1; break;
        case 2: in = p2; out = o2; n = n2; break;
        case 3: in = p3; out = o3; n = n3; break;
        default: in = p4; out = o4; n = n4; break;
    }
    const int stride = gridDim.x * blockDim.x;
    for (int i = blockIdx.x * blockDim.x + threadIdx.x; i < n / 4; i += stride) {
        float4 v = reinterpret_cast<const float4*>(in)[i];
        ushort4 r;
        r.x = f2bf(v.x); r.y = f2bf(v.y); r.z = f2bf(v.z); r.w = f2bf(v.w);
        reinterpret_cast<ushort4*>(out)[i] = r;
    }
}

// ---------------- bf16 MFMA GEMM: C[M,N] = A[M,K] @ W[N,K]^T ----------------
__global__ __launch_bounds__(256) void gemm_mfma_bt(
    const unsigned short* __restrict__ A,
    const unsigned short* __restrict__ W0, const unsigned short* __restrict__ W1,
    const unsigned short* __restrict__ W2,
    float* __restrict__ C0, float* __restrict__ C1, float* __restrict__ C2,
    int M, int N, int K)
{
    const unsigned short* W = blockIdx.z == 0 ? W0 : (blockIdx.z == 1 ? W1 : W2);
    float*                C = blockIdx.z == 0 ? C0 : (blockIdx.z == 1 ? C1 : C2);

    __shared__ unsigned short Als[128 * 64];
    __shared__ unsigned short Bls[128 * 64];

    const int tid = threadIdx.x;
    const int w   = tid >> 6;
    const int l   = tid & 63;
    const int bm  = blockIdx.y * 128;
    const int bn  = blockIdx.x * 128;
    const int wm  = (w >> 1) * 64;
    const int wn  = (w & 1) * 64;

    f32x4 acc[4][4];
    #pragma unroll
    for (int m = 0; m < 4; ++m)
        #pragma unroll
        for (int n = 0; n < 4; ++n) acc[m][n] = (f32x4){0.f, 0.f, 0.f, 0.f};

    const int frow = l & 15;
    const int kgrp = (l >> 4) * 16;
    const int swz  = (l & 7) << 4;

    const unsigned short* Ag = A + (size_t)bm * K;
    const unsigned short* Wg = W + (size_t)bn * K;

    for (int k0 = 0; k0 < K; k0 += 64) {
        __syncthreads();
        #pragma unroll
        for (int j = 0; j < 4; ++j) {
            const int idxb = j * 4096 + tid * 16;
            const int row  = idxb >> 7;
            const int kb   = idxb & 127;
            const int col  = (kb ^ ((row & 7) << 4)) >> 1;
            const int ldsb = j * 4096 + w * 1024;
            __builtin_amdgcn_global_load_lds(
                GPTR(Ag + (size_t)row * K + k0 + col),
                SPTR(Als + (ldsb >> 1)), 16, 0, 0);
            __builtin_amdgcn_global_load_lds(
                GPTR(Wg + (size_t)row * K + k0 + col),
                SPTR(Bls + (ldsb >> 1)), 16, 0, 0);
        }
        __syncthreads();

        #pragma unroll
        for (int ks = 0; ks < 2; ++ks) {
            bf16x8 af[4], bfr[4];
            #pragma unroll
            for (int m = 0; m < 4; ++m) {
                const int off = (wm + m * 16 + frow) * 128 + ((ks * 64 + kgrp) ^ swz);
                af[m] = *reinterpret_cast<const bf16x8*>((const char*)Als + off);
            }
            #pragma unroll
            for (int n = 0; n < 4; ++n) {
                const int off = (wn + n * 16 + frow) * 128 + ((ks * 64 + kgrp) ^ swz);
                bfr[n] = *reinterpret_cast<const bf16x8*>((const char*)Bls + off);
            }
            #pragma unroll
            for (int m = 0; m < 4; ++m)
                #pragma unroll
                for (int n = 0; n < 4; ++n)
                    acc[m][n] = __builtin_amdgcn_mfma_f32_16x16x32_bf16(
                        af[m], bfr[n], acc[m][n], 0, 0, 0);
        }
    }

    const int r0 = (l >> 4) * 4;
    const int cc = l & 15;
    #pragma unroll
    for (int m = 0; m < 4; ++m)
        #pragma unroll
        for (int n = 0; n < 4; ++n) {
            float* cp = C + (size_t)(bm + wm + m * 16 + r0) * N + bn + wn + n * 16 + cc;
            #pragma unroll
            for (int r = 0; r < 4; ++r) cp[(size_t)r * N] = acc[m][n][r];
        }
}

// ---------------- f = log_sigmoid(hs @ Wf^T + bf), [T,NH] ----------------
__global__ __launch_bounds__(256) void fproj(const float* __restrict__ hs,
                                             const float* __restrict__ Wf,
                                             const float* __restrict__ bf,
                                             float* __restrict__ f)
{
    const int t  = blockIdx.x;
    const int h  = threadIdx.x >> 4;
    const int sl = threadIdx.x & 15;
    const float4* hrow = reinterpret_cast<const float4*>(hs + (size_t)t * HID);
    const float4* wrow = reinterpret_cast<const float4*>(Wf + (size_t)h * HID);
    float s = 0.f;
    #pragma unroll
    for (int i = 0; i < 16; ++i) {
        float4 a = hrow[sl + i * 16];
        float4 b = wrow[sl + i * 16];
        s += a.x * b.x + a.y * b.y + a.z * b.z + a.w * b.w;
    }
    s += __shfl_xor(s, 1);
    s += __shfl_xor(s, 2);
    s += __shfl_xor(s, 4);
    s += __shfl_xor(s, 8);
    if (sl == 0) {
        float x = s + bf[h];
        f[t * NH + h] = (x >= 0.f) ? -log1pf(expf(-x)) : (x - log1pf(expf(x)));
    }
}

// ---------------- fwd/bwd inclusive cumsum, 4 waves x 512-elem segments ----------------
__global__ __launch_bounds__(256) void cumsum_f(const float* __restrict__ f,
                                                float* __restrict__ gcf,
                                                float* __restrict__ gcb)
{
    const int h   = blockIdx.x;
    const int rev = blockIdx.y;
    float* out = rev ? gcb : gcf;
    const int wv   = threadIdx.x >> 6;
    const int lane = threadIdx.x & 63;

    __shared__ float wtot[4];

    float vals[8];
    float run = 0.f;
    #pragma unroll
    for (int c = 0; c < 8; ++c) {
        const int p = wv * 512 + c * 64 + lane;
        const int t = rev ? (T_SEQ - 1 - p) : p;
        float x = f[t * NH + h];
        #pragma unroll
        for (int off = 1; off < 64; off <<= 1) {
            float y = __shfl_up(x, off);
            if (lane >= off) x += y;
        }
        vals[c] = run + x;
        run += __shfl(x, 63);
    }
    if (lane == 0) wtot[wv] = run;
    __syncthreads();
    float prefix = 0.f;
    #pragma unroll
    for (int i = 0; i < 4; ++i) prefix += (i < wv) ? wtot[i] : 0.f;
    #pragma unroll
    for (int c = 0; c < 8; ++c) {
        const int p = wv * 512 + c * 64 + lane;
        const int t = rev ? (T_SEQ - 1 - p) : p;
        out[t * NH + h] = vals[c] + prefix;
    }
}

// ---------------- per-head max ||k_row||_2 (256 threads) ----------------
__global__ __launch_bounds__(256) void knorms(const float* __restrict__ k,
                                              float* __restrict__ knmax)
{
    const int h   = blockIdx.x;
    const int tid = threadIdx.x;
    const int wv  = tid >> 6;
    const int lane = tid & 63;
    __shared__ float wmax[4];
    float mx = 0.f;
    for (int t = tid; t < T_SEQ; t += 256) {
        const float4* kr = reinterpret_cast<const float4*>(k + (size_t)t * HID + h * HD);
        float s = 0.f;
        #pragma unroll
        for (int i = 0; i < 16; ++i) {
            float4 a = kr[i];
            s += a.x * a.x + a.y * a.y + a.z * a.z + a.w * a.w;
        }
        mx = fmaxf(mx, s);
    }
    #pragma unroll
    for (int off = 32; off > 0; off >>= 1) mx = fmaxf(mx, __shfl_xor(mx, off));
    if (lane == 0) wmax[wv] = mx;
    __syncthreads();
    if (tid == 0) {
        float m = fmaxf(fmaxf(wmax[0], wmax[1]), fmaxf(wmax[2], wmax[3]));
        knmax[h] = sqrtf(m);
    }
}

// ---------------- MFMA flash attention with forgetting decay + early exit ----------
// Block = (qt, h, dir). 4 waves, wave w owns q-rows [16w,16w+16). Per k-tile:
// S = Q@K^T via mfma_16x16x32_bf16 (K,V staged bf16 in LDS, XOR-swizzled;
// V transposed so PV B-fragments are contiguous), tile-wise online softmax in
// C-layout (col=l&15, row=(l>>4)*4+reg), P->LDS bf16 (wave-private rows), PV MFMA.
__global__ __launch_bounds__(256) void attn_flash(
    const float* __restrict__ q, const float* __restrict__ k, const float* __restrict__ v,
    const float* __restrict__ gcf, const float* __restrict__ gcb,
    const float* __restrict__ knmax,
    unsigned short* __restrict__ ocat)
{
    const int dir = blockIdx.z;
    const float* gc = dir ? gcb : gcf;
    const int h   = blockIdx.y;
    const int qt  = blockIdx.x;
    const int q0  = qt * 64;
    const int tid = threadIdx.x;
    const int w   = tid >> 6;
    const int l   = tid & 63;
    const int lm  = l & 15;         // fragment row/col index
    const int lg  = l >> 4;         // k-group
    const int swz = (l & 7) << 4;   // XOR swizzle for b128 fragment reads

    __shared__ unsigned short Kls[64 * 64];   // [krow][d]
    __shared__ unsigned short Vls[64 * 64];   // transposed: [d][krow]
    __shared__ unsigned short Pls[64 * 64];   // [qrow][krow]
    __shared__ float gks[64];
    __shared__ float qbs[64];                 // per-row |q_scaled| * knmax

    // ---- Q fragments (A-operand), f32 load + scale + bf16 convert, once ----
    const int qrow_a = q0 + 16 * w + lm;
    bf16x8 aq[2];
    float qn2 = 0.f;
    #pragma unroll
    for (int ks = 0; ks < 2; ++ks) {
        const float4* src = reinterpret_cast<const float4*>(
            q + (size_t)qrow_a * HID + h * HD + ks * 32 + lg * 8);
        float4 a = src[0], b = src[1];
        float vv[8] = {a.x, a.y, a.z, a.w, b.x, b.y, b.z, b.w};
        #pragma unroll
        for (int j = 0; j < 8; ++j) {
            float sc = vv[j] * 0.125f;
            qn2 += sc * sc;
            unsigned short us = f2bf(sc);
            aq[ks][j] = *reinterpret_cast<__bf16*>(&us);
        }
    }
    qn2 += __shfl_xor(qn2, 16);
    qn2 += __shfl_xor(qn2, 32);
    if (lg == 0) qbs[16 * w + lm] = sqrtf(qn2) * knmax[h];

    // decay for this lane's softmax rows (C-layout rows)
    float gq_r[4];
    #pragma unroll
    for (int reg = 0; reg < 4; ++reg)
        gq_r[reg] = gc[(q0 + 16 * w + lg * 4 + reg) * NH + h];

    float mrun[4], lrun[4];
    #pragma unroll
    for (int reg = 0; reg < 4; ++reg) { mrun[reg] = -1e30f; lrun[reg] = 0.f; }
    f32x4 acc[4];
    #pragma unroll
    for (int db = 0; db < 4; ++db) acc[db] = (f32x4){0.f, 0.f, 0.f, 0.f};

    const int stp = dir ? 1 : -1;
    for (int kt = qt; kt >= 0 && kt < NT; kt += stp) {
        const int k0 = kt * 64;
        __syncthreads();   // previous tile's LDS reads complete

        // ---- stage K tile: [krow][d] bf16, swizzled; 16B packed writes ----
        {
            const int row = tid >> 2, dg = tid & 3;
            const float4* src = reinterpret_cast<const float4*>(
                k + (size_t)(k0 + row) * HID + h * HD + dg * 16);
            float4 a = src[0], b = src[1], c = src[2], d4 = src[3];
            float vv[16] = {a.x, a.y, a.z, a.w, b.x, b.y, b.z, b.w,
                            c.x, c.y, c.z, c.w, d4.x, d4.y, d4.z, d4.w};
            u16x8 lo, hi;
            #pragma unroll
            for (int j = 0; j < 8; ++j) { lo[j] = f2bf(vv[j]); hi[j] = f2bf(vv[j + 8]); }
            const int rs = (row & 7) << 4;
            *reinterpret_cast<u16x8*>((char*)Kls + row * 128 + ((dg * 32) ^ rs))      = lo;
            *reinterpret_cast<u16x8*>((char*)Kls + row * 128 + ((dg * 32 + 16) ^ rs)) = hi;
        }
        // ---- stage V transposed: [d][krow], packed u32 (k,k+1), swizzled ----
        {
            const int kp = tid & 31, dg = tid >> 5;   // k = 2kp,2kp+1; d in [dg*8, dg*8+8)
            const int kk = kp * 2;
            const float4* s0 = reinterpret_cast<const float4*>(
                v + (size_t)(k0 + kk) * HID + h * HD + dg * 8);
            const float4* s1 = reinterpret_cast<const float4*>(
                v + (size_t)(k0 + kk + 1) * HID + h * HD + dg * 8);
            float4 a0 = s0[0], a1 = s0[1];
            float4 b0 = s1[0], b1 = s1[1];
            float va[8] = {a0.x, a0.y, a0.z, a0.w, a1.x, a1.y, a1.z, a1.w};
            float vb[8] = {b0.x, b0.y, b0.z, b0.w, b1.x, b1.y, b1.z, b1.w};
            #pragma unroll
            for (int j = 0; j < 8; ++j) {
                const int d = dg * 8 + j;
                unsigned pack = (unsigned)f2bf(va[j]) | ((unsigned)f2bf(vb[j]) << 16);
                *reinterpret_cast<unsigned*>((char*)Vls + d * 128 + ((kk * 2) ^ ((d & 7) << 4))) = pack;
            }
        }
        if (tid < 64) gks[tid] = gc[(k0 + tid) * NH + h];
        __syncthreads();

        // ---- S = Q @ K^T (per wave: 16 rows x 64 cols) ----
        f32x4 s[4];
        #pragma unroll
        for (int cb = 0; cb < 4; ++cb) {
            bf16x8 b0 = *reinterpret_cast<const bf16x8*>(
                (char*)Kls + (cb * 16 + lm) * 128 + ((lg * 16) ^ swz));
            bf16x8 b1 = *reinterpret_cast<const bf16x8*>(
                (char*)Kls + (cb * 16 + lm) * 128 + ((64 + lg * 16) ^ swz));
            f32x4 z = (f32x4){0.f, 0.f, 0.f, 0.f};
            z = __builtin_amdgcn_mfma_f32_16x16x32_bf16(aq[0], b0, z, 0, 0, 0);
            s[cb] = __builtin_amdgcn_mfma_f32_16x16x32_bf16(aq[1], b1, z, 0, 0, 0);
        }

        // ---- decay + mask ----
        float gk_c[4];
        #pragma unroll
        for (int cb = 0; cb < 4; ++cb) gk_c[cb] = gks[cb * 16 + lm];
        float sv[4][4];
        const bool diag = (kt == qt);
        #pragma unroll
        for (int cb = 0; cb < 4; ++cb)
            #pragma unroll
            for (int reg = 0; reg < 4; ++reg) {
                float x = s[cb][reg] + gq_r[reg] - gk_c[cb];
                if (diag) {
                    const int c_loc = cb * 16 + lm;
                    const int r_loc = 16 * w + lg * 4 + reg;
                    const bool valid = dir ? (c_loc >= r_loc) : (c_loc <= r_loc);
                    x = valid ? x : -1e30f;
                }
                sv[cb][reg] = x;
            }

        // ---- tile-wise online softmax ----
        float corr[4], mnew[4];
        #pragma unroll
        for (int reg = 0; reg < 4; ++reg) {
            float rm = fmaxf(fmaxf(sv[0][reg], sv[1][reg]), fmaxf(sv[2][reg], sv[3][reg]));
            rm = fmaxf(rm, __shfl_xor(rm, 1));
            rm = fmaxf(rm, __shfl_xor(rm, 2));
            rm = fmaxf(rm, __shfl_xor(rm, 4));
            rm = fmaxf(rm, __shfl_xor(rm, 8));
            mnew[reg] = fmaxf(mrun[reg], rm);
            corr[reg] = __expf(mrun[reg] - mnew[reg]);
            mrun[reg] = mnew[reg];
        }
        float psum[4] = {0.f, 0.f, 0.f, 0.f};
        #pragma unroll
        for (int cb = 0; cb < 4; ++cb)
            #pragma unroll
            for (int reg = 0; reg < 4; ++reg) {
                const float p = __expf(sv[cb][reg] - mnew[reg]);
                psum[reg] += p;
                const int r_loc = 16 * w + lg * 4 + reg;
                *reinterpret_cast<unsigned short*>(
                    (char*)Pls + r_loc * 128 + ((cb * 32 + lm * 2) ^ ((r_loc & 7) << 4))) = f2bf(p);
            }
        #pragma unroll
        for (int reg = 0; reg < 4; ++reg) {
            float ps = psum[reg];
            ps += __shfl_xor(ps, 1);
            ps += __shfl_xor(ps, 2);
            ps += __shfl_xor(ps, 4);
            ps += __shfl_xor(ps, 8);
            lrun[reg] = lrun[reg] * corr[reg] + ps;
        }
        #pragma unroll
        for (int db = 0; db < 4; ++db)
            #pragma unroll
            for (int reg = 0; reg < 4; ++reg) acc[db][reg] *= corr[reg];

        // ---- PV: acc += P @ V (wave-private P rows; no cross-wave sync) ----
        bf16x8 ap[2];
        #pragma unroll
        for (int ks = 0; ks < 2; ++ks)
            ap[ks] = *reinterpret_cast<const bf16x8*>(
                (char*)Pls + (16 * w + lm) * 128 + ((ks * 64 + lg * 16) ^ swz));
        #pragma unroll
        for (int db = 0; db < 4; ++db) {
            bf16x8 bv0 = *reinterpret_cast<const bf16x8*>(
                (char*)Vls + (db * 16 + lm) * 128 + ((lg * 16) ^ swz));
            bf16x8 bv1 = *reinterpret_cast<const bf16x8*>(
                (char*)Vls + (db * 16 + lm) * 128 + ((64 + lg * 16) ^ swz));
            acc[db] = __builtin_amdgcn_mfma_f32_16x16x32_bf16(ap[0], bv0, acc[db], 0, 0, 0);
            acc[db] = __builtin_amdgcn_mfma_f32_16x16x32_bf16(ap[1], bv1, acc[db], 0, 0, 0);
        }

        // ---- early-exit vote for the next (more distant) tile ----
        const int nkt = kt + stp;
        if (nkt >= 0 && nkt < NT) {
            const float gkedge = dir ? gc[(nkt * 64) * NH + h]
                                     : gc[(nkt * 64 + 63) * NH + h];
            int pred = 0;
            #pragma unroll
            for (int reg = 0; reg < 4; ++reg) {
                const float qb = qbs[16 * w + lg * 4 + reg];
                pred |= (qb + gq_r[reg] - gkedge) >= (mrun[reg] - 15.f);
            }
            if (!__syncthreads_or(pred)) break;
        }
    }

    // ---- epilogue: normalize + bf16 store ----
    float inv[4];
    #pragma unroll
    for (int reg = 0; reg < 4; ++reg) inv[reg] = 1.f / lrun[reg];
    #pragma unroll
    for (int db = 0; db < 4; ++db)
        #pragma unroll
        for (int reg = 0; reg < 4; ++reg) {
            const int row = q0 + 16 * w + lg * 4 + reg;
            const int col = db * 16 + lm;
            ocat[(size_t)row * (2 * HID) + dir * HID + h * HD + col] =
                f2bf(acc[db][reg] * inv[reg]);
        }
}

// ---------------- launch ----------------
extern "C" void kernel_launch(void* const* d_in, const int* in_sizes, int n_in,
                              void* d_out, int out_size, void* d_ws, size_t ws_size,
                              hipStream_t stream)
{
    (void)in_sizes; (void)n_in; (void)out_size; (void)ws_size;
    const float* hs = (const float*)d_in[0];
    const float* Wq = (const float*)d_in[1];
    const float* Wk = (const float*)d_in[2];
    const float* Wv = (const float*)d_in[3];
    const float* Wf = (const float*)d_in[4];
    const float* bf = (const float*)d_in[5];
    const float* Wo = (const float*)d_in[6];
    float* out = (float*)d_out;

    float* ws    = (float*)d_ws;
    float* q     = ws;
    float* k     = q     + (size_t)T_SEQ * HID;
    float* v     = k     + (size_t)T_SEQ * HID;
    float* f     = v     + (size_t)T_SEQ * HID;
    float* gcf   = f     + (size_t)T_SEQ * NH;
    float* gcb   = gcf   + (size_t)T_SEQ * NH;
    float* knmax = gcb   + (size_t)T_SEQ * NH;
    unsigned short* hsb  = (unsigned short*)(knmax + 64);
    unsigned short* wqb  = hsb + (size_t)T_SEQ * HID;
    unsigned short* wkb  = wqb + (size_t)HID * HID;
    unsigned short* wvb  = wkb + (size_t)HID * HID;
    unsigned short* wob  = wvb + (size_t)HID * HID;
    unsigned short* ocat = wob + (size_t)HID * 2 * HID;

    f2bf_multi<<<dim3(256, 5), 256, 0, stream>>>(
        hs, Wq, Wk, Wv, Wo, hsb, wqb, wkb, wvb, wob,
        T_SEQ * HID, HID * HID, HID * HID, HID * HID, HID * 2 * HID);

    gemm_mfma_bt<<<dim3(HID / 128, T_SEQ / 128, 3), 256, 0, stream>>>(
        hsb, wqb, wkb, wvb, q, k, v, T_SEQ, HID, HID);

    fproj<<<T_SEQ, 256, 0, stream>>>(hs, Wf, bf, f);
    cumsum_f<<<dim3(NH, 2), 256, 0, stream>>>(f, gcf, gcb);
    knorms<<<NH, 256, 0, stream>>>(k, knmax);

    attn_flash<<<dim3(NT, NH, 2), 256, 0, stream>>>(q, k, v, gcf, gcb, knmax, ocat);

    gemm_mfma_bt<<<dim3(HID / 128, T_SEQ / 128, 1), 256, 0, stream>>>(
        ocat, wob, nullptr, nullptr, out, nullptr, nullptr, T_SEQ, HID, 2 * HID);
}

// Round 6
// 118.946 us; speedup vs baseline: 14.1195x; 1.1165x over previous
//
#include <hip/hip_runtime.h>
#include <math.h>

#define T_SEQ 2048
#define HID   1024
#define NH    16
#define HD    64
#define NT    (T_SEQ / 64)

typedef __attribute__((ext_vector_type(8))) __bf16 bf16x8;
typedef __attribute__((ext_vector_type(4))) float  f32x4;
typedef __attribute__((ext_vector_type(8))) unsigned short u16x8;

#define GPTR(p) (const __attribute__((address_space(1))) void*)(p)
#define SPTR(p) (__attribute__((address_space(3))) void*)(p)

__device__ __forceinline__ unsigned short f2bf(float x) {
    unsigned u = __float_as_uint(x);
    u = (u + 0x7FFF + ((u >> 16) & 1)) >> 16;   // RNE
    return (unsigned short)u;
}
__device__ __forceinline__ float bf2f(unsigned short u) {
    return __uint_as_float((unsigned)u << 16);
}

// ---------------- f32 -> bf16 conversion (5 segments) ----------------
__global__ __launch_bounds__(256) void f2bf_multi(
    const float* __restrict__ p0, const float* __restrict__ p1,
    const float* __restrict__ p2, const float* __restrict__ p3,
    const float* __restrict__ p4,
    unsigned short* o0, unsigned short* o1, unsigned short* o2,
    unsigned short* o3, unsigned short* o4,
    int n0, int n1, int n2, int n3, int n4)
{
    const float* in; unsigned short* out; int n;
    switch (blockIdx.y) {
        case 0: in = p0; out = o0; n = n0; break;
        case 1: in = p1; out = o1; n = n1; break;
        case 2: in = p2; out = o2; n = n2; break;
        case 3: in = p3; out = o3; n = n3; break;
        default: in = p4; out = o4; n = n4; break;
    }
    const int stride = gridDim.x * blockDim.x;
    for (int i = blockIdx.x * blockDim.x + threadIdx.x; i < n / 4; i += stride) {
        float4 v = reinterpret_cast<const float4*>(in)[i];
        ushort4 r;
        r.x = f2bf(v.x); r.y = f2bf(v.y); r.z = f2bf(v.z); r.w = f2bf(v.w);
        reinterpret_cast<ushort4*>(out)[i] = r;
    }
}

// ---------------- bf16 MFMA GEMM: C = A @ W^T ----------------
// emode 0 (qkv): z=0 -> qb [T][HID] bf16 *0.125; z=1 -> kb [NH][T][64] bf16;
//                z=2 -> vt [NH][64][T] bf16 (transposed, packed stores).
// emode 1: f32 C store (output projection).
__global__ __launch_bounds__(256) void gemm_mfma_bt(
    const unsigned short* __restrict__ A,
    const unsigned short* __restrict__ W0, const unsigned short* __restrict__ W1,
    const unsigned short* __restrict__ W2,
    float* __restrict__ C,
    unsigned short* __restrict__ qb, unsigned short* __restrict__ kb,
    unsigned short* __restrict__ vt,
    int M, int N, int K, int emode)
{
    const unsigned short* W = blockIdx.z == 0 ? W0 : (blockIdx.z == 1 ? W1 : W2);

    __shared__ unsigned short Als[128 * 64];
    __shared__ unsigned short Bls[128 * 64];

    const int tid = threadIdx.x;
    const int w   = tid >> 6;
    const int l   = tid & 63;
    const int bm  = blockIdx.y * 128;
    const int bn  = blockIdx.x * 128;
    const int wm  = (w >> 1) * 64;
    const int wn  = (w & 1) * 64;

    f32x4 acc[4][4];
    #pragma unroll
    for (int m = 0; m < 4; ++m)
        #pragma unroll
        for (int n = 0; n < 4; ++n) acc[m][n] = (f32x4){0.f, 0.f, 0.f, 0.f};

    const int frow = l & 15;
    const int kgrp = (l >> 4) * 16;
    const int swz  = (l & 7) << 4;

    const unsigned short* Ag = A + (size_t)bm * K;
    const unsigned short* Wg = W + (size_t)bn * K;

    for (int k0 = 0; k0 < K; k0 += 64) {
        __syncthreads();
        #pragma unroll
        for (int j = 0; j < 4; ++j) {
            const int idxb = j * 4096 + tid * 16;
            const int row  = idxb >> 7;
            const int kbyt = idxb & 127;
            const int col  = (kbyt ^ ((row & 7) << 4)) >> 1;
            const int ldsh = (j * 4096 + w * 1024) >> 1;
            __builtin_amdgcn_global_load_lds(
                GPTR(Ag + (size_t)row * K + k0 + col), SPTR(Als + ldsh), 16, 0, 0);
            __builtin_amdgcn_global_load_lds(
                GPTR(Wg + (size_t)row * K + k0 + col), SPTR(Bls + ldsh), 16, 0, 0);
        }
        __syncthreads();

        #pragma unroll
        for (int ks = 0; ks < 2; ++ks) {
            bf16x8 af[4], bfr[4];
            #pragma unroll
            for (int m = 0; m < 4; ++m) {
                const int off = (wm + m * 16 + frow) * 128 + ((ks * 64 + kgrp) ^ swz);
                af[m] = *reinterpret_cast<const bf16x8*>((const char*)Als + off);
            }
            #pragma unroll
            for (int n = 0; n < 4; ++n) {
                const int off = (wn + n * 16 + frow) * 128 + ((ks * 64 + kgrp) ^ swz);
                bfr[n] = *reinterpret_cast<const bf16x8*>((const char*)Bls + off);
            }
            #pragma unroll
            for (int m = 0; m < 4; ++m)
                #pragma unroll
                for (int n = 0; n < 4; ++n)
                    acc[m][n] = __builtin_amdgcn_mfma_f32_16x16x32_bf16(
                        af[m], bfr[n], acc[m][n], 0, 0, 0);
        }
    }

    const int r0 = (l >> 4) * 4;
    const int cc = l & 15;
    if (emode == 1) {
        #pragma unroll
        for (int m = 0; m < 4; ++m)
            #pragma unroll
            for (int n = 0; n < 4; ++n) {
                float* cp = C + (size_t)(bm + wm + m * 16 + r0) * N + bn + wn + n * 16 + cc;
                #pragma unroll
                for (int r = 0; r < 4; ++r) cp[(size_t)r * N] = acc[m][n][r];
            }
    } else {
        const int z    = blockIdx.z;
        const int col0 = bn + wn;
        const int hh   = col0 >> 6;
        if (z == 0) {
            #pragma unroll
            for (int m = 0; m < 4; ++m) {
                const int t0 = bm + wm + m * 16 + r0;
                #pragma unroll
                for (int n = 0; n < 4; ++n) {
                    const int col = col0 + n * 16 + cc;
                    #pragma unroll
                    for (int r = 0; r < 4; ++r)
                        qb[(size_t)(t0 + r) * HID + col] = f2bf(acc[m][n][r] * 0.125f);
                }
            }
        } else if (z == 1) {
            #pragma unroll
            for (int m = 0; m < 4; ++m) {
                const int t0 = bm + wm + m * 16 + r0;
                #pragma unroll
                for (int n = 0; n < 4; ++n) {
                    const int d = n * 16 + cc;
                    #pragma unroll
                    for (int r = 0; r < 4; ++r)
                        kb[(size_t)hh * T_SEQ * HD + (size_t)(t0 + r) * HD + d] =
                            f2bf(acc[m][n][r]);
                }
            }
        } else {
            #pragma unroll
            for (int m = 0; m < 4; ++m) {
                const int t0 = bm + wm + m * 16 + r0;
                #pragma unroll
                for (int n = 0; n < 4; ++n) {
                    const int d = n * 16 + cc;
                    ushort4 pk;
                    pk.x = f2bf(acc[m][n][0]); pk.y = f2bf(acc[m][n][1]);
                    pk.z = f2bf(acc[m][n][2]); pk.w = f2bf(acc[m][n][3]);
                    *reinterpret_cast<ushort4*>(
                        vt + (size_t)hh * HD * T_SEQ + (size_t)d * T_SEQ + t0) = pk;
                }
            }
        }
    }
}

// ---------------- f = log_sigmoid(hs @ Wf^T + bf), [T,NH] ----------------
__global__ __launch_bounds__(256) void fproj(const float* __restrict__ hs,
                                             const float* __restrict__ Wf,
                                             const float* __restrict__ bf,
                                             float* __restrict__ f)
{
    const int t  = blockIdx.x;
    const int h  = threadIdx.x >> 4;
    const int sl = threadIdx.x & 15;
    const float4* hrow = reinterpret_cast<const float4*>(hs + (size_t)t * HID);
    const float4* wrow = reinterpret_cast<const float4*>(Wf + (size_t)h * HID);
    float s = 0.f;
    #pragma unroll
    for (int i = 0; i < 16; ++i) {
        float4 a = hrow[sl + i * 16];
        float4 b = wrow[sl + i * 16];
        s += a.x * b.x + a.y * b.y + a.z * b.z + a.w * b.w;
    }
    s += __shfl_xor(s, 1);
    s += __shfl_xor(s, 2);
    s += __shfl_xor(s, 4);
    s += __shfl_xor(s, 8);
    if (sl == 0) {
        float x = s + bf[h];
        f[t * NH + h] = (x >= 0.f) ? -log1pf(expf(-x)) : (x - log1pf(expf(x)));
    }
}

// ---------------- fwd/bwd inclusive cumsum, 4 waves x 512-elem segments ----------------
__global__ __launch_bounds__(256) void cumsum_f(const float* __restrict__ f,
                                                float* __restrict__ gcf,
                                                float* __restrict__ gcb)
{
    const int h   = blockIdx.x;
    const int rev = blockIdx.y;
    float* out = rev ? gcb : gcf;
    const int wv   = threadIdx.x >> 6;
    const int lane = threadIdx.x & 63;

    __shared__ float wtot[4];

    float vals[8];
    float run = 0.f;
    #pragma unroll
    for (int c = 0; c < 8; ++c) {
        const int p = wv * 512 + c * 64 + lane;
        const int t = rev ? (T_SEQ - 1 - p) : p;
        float x = f[t * NH + h];
        #pragma unroll
        for (int off = 1; off < 64; off <<= 1) {
            float y = __shfl_up(x, off);
            if (lane >= off) x += y;
        }
        vals[c] = run + x;
        run += __shfl(x, 63);
    }
    if (lane == 0) wtot[wv] = run;
    __syncthreads();
    float prefix = 0.f;
    #pragma unroll
    for (int i = 0; i < 4; ++i) prefix += (i < wv) ? wtot[i] : 0.f;
    #pragma unroll
    for (int c = 0; c < 8; ++c) {
        const int p = wv * 512 + c * 64 + lane;
        const int t = rev ? (T_SEQ - 1 - p) : p;
        out[t * NH + h] = vals[c] + prefix;
    }
}

// ---------------- per-head max ||k_row||_2 from bf16 kb [NH][T][64] ----------------
__global__ __launch_bounds__(256) void knorms(const unsigned short* __restrict__ kb,
                                              float* __restrict__ knmax)
{
    const int h    = blockIdx.x;
    const int tid  = threadIdx.x;
    const int wv   = tid >> 6;
    const int lane = tid & 63;
    __shared__ float wmax[4];
    float mx = 0.f;
    for (int t = tid; t < T_SEQ; t += 256) {
        const u16x8* kr = reinterpret_cast<const u16x8*>(
            kb + (size_t)h * T_SEQ * HD + (size_t)t * HD);
        float s = 0.f;
        #pragma unroll
        for (int i = 0; i < 8; ++i) {
            u16x8 v8 = kr[i];
            #pragma unroll
            for (int j = 0; j < 8; ++j) { float x = bf2f(v8[j]); s += x * x; }
        }
        mx = fmaxf(mx, s);
    }
    #pragma unroll
    for (int off = 32; off > 0; off >>= 1) mx = fmaxf(mx, __shfl_xor(mx, off));
    if (lane == 0) wmax[wv] = mx;
    __syncthreads();
    if (tid == 0) {
        float m = fmaxf(fmaxf(wmax[0], wmax[1]), fmaxf(wmax[2], wmax[3]));
        knmax[h] = sqrtf(m);
    }
}

// ---------------- MFMA flash attention, bf16-native inputs ----------------
// qb [T][HID] bf16 (pre-scaled), kb [NH][T][64] bf16, vt [NH][64][T] bf16.
// Staging = pure global_load_lds (16B, inverse-swizzled source). 2 barriers/tile.
__global__ __launch_bounds__(256) void attn_flash(
    const unsigned short* __restrict__ qb, const unsigned short* __restrict__ kg,
    const unsigned short* __restrict__ vg,
    const float* __restrict__ gcf, const float* __restrict__ gcb,
    const float* __restrict__ knmax,
    unsigned short* __restrict__ ocat)
{
    const int dir = blockIdx.z;
    const float* gc = dir ? gcb : gcf;
    const int h   = blockIdx.y;
    const int qt  = blockIdx.x;
    const int q0  = qt * 64;
    const int tid = threadIdx.x;
    const int w   = tid >> 6;
    const int l   = tid & 63;
    const int lm  = l & 15;
    const int lg  = l >> 4;
    const int swz = (l & 7) << 4;

    __shared__ unsigned short Kls[64 * 64];   // [krow][d] swizzled
    __shared__ unsigned short Vls[64 * 64];   // [d][krow] swizzled
    __shared__ unsigned short Pls[64 * 64];   // [qrow][krow] swizzled
    __shared__ float gks[64];
    __shared__ float qbs[64];

    const size_t kgbase = (size_t)h * T_SEQ * HD;
    const size_t vgbase = (size_t)h * HD * T_SEQ;

    // ---- Q fragments: direct bf16 16B loads (pre-scaled by 0.125) ----
    const int qrow_a = q0 + 16 * w + lm;
    bf16x8 aq[2];
    aq[0] = *reinterpret_cast<const bf16x8*>(qb + (size_t)qrow_a * HID + h * HD + lg * 8);
    aq[1] = *reinterpret_cast<const bf16x8*>(qb + (size_t)qrow_a * HID + h * HD + 32 + lg * 8);
    float qn2 = 0.f;
    #pragma unroll
    for (int ks = 0; ks < 2; ++ks) {
        u16x8 uv = *reinterpret_cast<const u16x8*>(&aq[ks]);
        #pragma unroll
        for (int j = 0; j < 8; ++j) { float x = bf2f(uv[j]); qn2 += x * x; }
    }
    qn2 += __shfl_xor(qn2, 16);
    qn2 += __shfl_xor(qn2, 32);
    if (lg == 0) qbs[16 * w + lm] = sqrtf(qn2) * knmax[h];

    float gq_r[4];
    #pragma unroll
    for (int reg = 0; reg < 4; ++reg)
        gq_r[reg] = gc[(q0 + 16 * w + lg * 4 + reg) * NH + h];

    float mrun[4], lrun[4];
    #pragma unroll
    for (int reg = 0; reg < 4; ++reg) { mrun[reg] = -1e30f; lrun[reg] = 0.f; }
    f32x4 acc[4];
    #pragma unroll
    for (int db = 0; db < 4; ++db) acc[db] = (f32x4){0.f, 0.f, 0.f, 0.f};

    const int stp = dir ? 1 : -1;
    for (int kt = qt; kt >= 0 && kt < NT; kt += stp) {
        const int k0 = kt * 64;

        // ---- stage K/V tiles + gc (pure global_load_lds, swizzled source) ----
        #pragma unroll
        for (int j = 0; j < 2; ++j) {
            const int idxb = j * 4096 + tid * 16;
            const int row  = idxb >> 7;
            const int kbyt = idxb & 127;
            const int scol = (kbyt ^ ((row & 7) << 4)) >> 1;
            const int ldsh = (j * 4096 + w * 1024) >> 1;
            __builtin_amdgcn_global_load_lds(
                GPTR(kg + kgbase + (size_t)(k0 + row) * HD + scol),
                SPTR(Kls + ldsh), 16, 0, 0);
            __builtin_amdgcn_global_load_lds(
                GPTR(vg + vgbase + (size_t)row * T_SEQ + k0 + scol),
                SPTR(Vls + ldsh), 16, 0, 0);
        }
        if (w == 0)
            __builtin_amdgcn_global_load_lds(
                GPTR(gc + (size_t)(k0 + l) * NH + h), SPTR(gks), 4, 0, 0);
        __syncthreads();   // staged (implicit vmcnt drain) + prior reads done

        // ---- S = Q @ K^T ----
        f32x4 s[4];
        #pragma unroll
        for (int cb = 0; cb < 4; ++cb) {
            bf16x8 b0 = *reinterpret_cast<const bf16x8*>(
                (char*)Kls + (cb * 16 + lm) * 128 + ((lg * 16) ^ swz));
            bf16x8 b1 = *reinterpret_cast<const bf16x8*>(
                (char*)Kls + (cb * 16 + lm) * 128 + ((64 + lg * 16) ^ swz));
            f32x4 z = (f32x4){0.f, 0.f, 0.f, 0.f};
            z = __builtin_amdgcn_mfma_f32_16x16x32_bf16(aq[0], b0, z, 0, 0, 0);
            s[cb] = __builtin_amdgcn_mfma_f32_16x16x32_bf16(aq[1], b1, z, 0, 0, 0);
        }

        // ---- decay + mask ----
        float gk_c[4];
        #pragma unroll
        for (int cb = 0; cb < 4; ++cb) gk_c[cb] = gks[cb * 16 + lm];
        float sv[4][4];
        const bool diag = (kt == qt);
        #pragma unroll
        for (int cb = 0; cb < 4; ++cb)
            #pragma unroll
            for (int reg = 0; reg < 4; ++reg) {
                float x = s[cb][reg] + gq_r[reg] - gk_c[cb];
                if (diag) {
                    const int c_loc = cb * 16 + lm;
                    const int r_loc = 16 * w + lg * 4 + reg;
                    const bool valid = dir ? (c_loc >= r_loc) : (c_loc <= r_loc);
                    x = valid ? x : -1e30f;
                }
                sv[cb][reg] = x;
            }

        // ---- tile-wise online softmax ----
        float corr[4], mnew[4];
        #pragma unroll
        for (int reg = 0; reg < 4; ++reg) {
            float rm = fmaxf(fmaxf(sv[0][reg], sv[1][reg]), fmaxf(sv[2][reg], sv[3][reg]));
            rm = fmaxf(rm, __shfl_xor(rm, 1));
            rm = fmaxf(rm, __shfl_xor(rm, 2));
            rm = fmaxf(rm, __shfl_xor(rm, 4));
            rm = fmaxf(rm, __shfl_xor(rm, 8));
            mnew[reg] = fmaxf(mrun[reg], rm);
            corr[reg] = __expf(mrun[reg] - mnew[reg]);
            mrun[reg] = mnew[reg];
        }
        float psum[4] = {0.f, 0.f, 0.f, 0.f};
        #pragma unroll
        for (int cb = 0; cb < 4; ++cb)
            #pragma unroll
            for (int reg = 0; reg < 4; ++reg) {
                const float p = __expf(sv[cb][reg] - mnew[reg]);
                psum[reg] += p;
                const int r_loc = 16 * w + lg * 4 + reg;
                *reinterpret_cast<unsigned short*>(
                    (char*)Pls + r_loc * 128 + ((cb * 32 + lm * 2) ^ ((r_loc & 7) << 4))) = f2bf(p);
            }
        #pragma unroll
        for (int reg = 0; reg < 4; ++reg) {
            float ps = psum[reg];
            ps += __shfl_xor(ps, 1);
            ps += __shfl_xor(ps, 2);
            ps += __shfl_xor(ps, 4);
            ps += __shfl_xor(ps, 8);
            lrun[reg] = lrun[reg] * corr[reg] + ps;
        }
        #pragma unroll
        for (int db = 0; db < 4; ++db)
            #pragma unroll
            for (int reg = 0; reg < 4; ++reg) acc[db][reg] *= corr[reg];

        // ---- PV ----
        bf16x8 ap[2];
        #pragma unroll
        for (int ks = 0; ks < 2; ++ks)
            ap[ks] = *reinterpret_cast<const bf16x8*>(
                (char*)Pls + (16 * w + lm) * 128 + ((ks * 64 + lg * 16) ^ swz));
        #pragma unroll
        for (int db = 0; db < 4; ++db) {
            bf16x8 bv0 = *reinterpret_cast<const bf16x8*>(
                (char*)Vls + (db * 16 + lm) * 128 + ((lg * 16) ^ swz));
            bf16x8 bv1 = *reinterpret_cast<const bf16x8*>(
                (char*)Vls + (db * 16 + lm) * 128 + ((64 + lg * 16) ^ swz));
            acc[db] = __builtin_amdgcn_mfma_f32_16x16x32_bf16(ap[0], bv0, acc[db], 0, 0, 0);
            acc[db] = __builtin_amdgcn_mfma_f32_16x16x32_bf16(ap[1], bv1, acc[db], 0, 0, 0);
        }

        // ---- early-exit vote (doubles as end-of-tile barrier) ----
        const int nkt = kt + stp;
        if (nkt >= 0 && nkt < NT) {
            const float gkedge = dir ? gc[(nkt * 64) * NH + h]
                                     : gc[(nkt * 64 + 63) * NH + h];
            int pred = 0;
            #pragma unroll
            for (int reg = 0; reg < 4; ++reg) {
                const float qbv = qbs[16 * w + lg * 4 + reg];
                pred |= (qbv + gq_r[reg] - gkedge) >= (mrun[reg] - 15.f);
            }
            if (!__syncthreads_or(pred)) break;
        }
    }

    // ---- epilogue ----
    float inv[4];
    #pragma unroll
    for (int reg = 0; reg < 4; ++reg) inv[reg] = 1.f / lrun[reg];
    #pragma unroll
    for (int db = 0; db < 4; ++db)
        #pragma unroll
        for (int reg = 0; reg < 4; ++reg) {
            const int row = q0 + 16 * w + lg * 4 + reg;
            const int col = db * 16 + lm;
            ocat[(size_t)row * (2 * HID) + dir * HID + h * HD + col] =
                f2bf(acc[db][reg] * inv[reg]);
        }
}

// ---------------- launch ----------------
extern "C" void kernel_launch(void* const* d_in, const int* in_sizes, int n_in,
                              void* d_out, int out_size, void* d_ws, size_t ws_size,
                              hipStream_t stream)
{
    (void)in_sizes; (void)n_in; (void)out_size; (void)ws_size;
    const float* hs = (const float*)d_in[0];
    const float* Wq = (const float*)d_in[1];
    const float* Wk = (const float*)d_in[2];
    const float* Wv = (const float*)d_in[3];
    const float* Wf = (const float*)d_in[4];
    const float* bf = (const float*)d_in[5];
    const float* Wo = (const float*)d_in[6];
    float* out = (float*)d_out;

    float* ws    = (float*)d_ws;
    float* f     = ws;
    float* gcf   = f   + (size_t)T_SEQ * NH;
    float* gcb   = gcf + (size_t)T_SEQ * NH;
    float* knmax = gcb + (size_t)T_SEQ * NH;
    unsigned short* hsb  = (unsigned short*)(knmax + 64);
    unsigned short* wqb  = hsb + (size_t)T_SEQ * HID;
    unsigned short* wkb  = wqb + (size_t)HID * HID;
    unsigned short* wvb  = wkb + (size_t)HID * HID;
    unsigned short* wob  = wvb + (size_t)HID * HID;
    unsigned short* qb   = wob + (size_t)HID * 2 * HID;
    unsigned short* kb   = qb  + (size_t)T_SEQ * HID;
    unsigned short* vt   = kb  + (size_t)T_SEQ * HID;
    unsigned short* ocat = vt  + (size_t)T_SEQ * HID;

    f2bf_multi<<<dim3(256, 5), 256, 0, stream>>>(
        hs, Wq, Wk, Wv, Wo, hsb, wqb, wkb, wvb, wob,
        T_SEQ * HID, HID * HID, HID * HID, HID * HID, HID * 2 * HID);

    // qkv projections -> attention-native bf16 layouts
    gemm_mfma_bt<<<dim3(HID / 128, T_SEQ / 128, 3), 256, 0, stream>>>(
        hsb, wqb, wkb, wvb, nullptr, qb, kb, vt, T_SEQ, HID, HID, 0);

    fproj<<<T_SEQ, 256, 0, stream>>>(hs, Wf, bf, f);
    cumsum_f<<<dim3(NH, 2), 256, 0, stream>>>(f, gcf, gcb);
    knorms<<<NH, 256, 0, stream>>>(kb, knmax);

    attn_flash<<<dim3(NT, NH, 2), 256, 0, stream>>>(qb, kb, vt, gcf, gcb, knmax, ocat);

    // out = ocat @ Wo^T (f32 store)
    gemm_mfma_bt<<<dim3(HID / 128, T_SEQ / 128, 1), 256, 0, stream>>>(
        ocat, wob, nullptr, nullptr, out, nullptr, nullptr, nullptr,
        T_SEQ, HID, 2 * HID, 1);
}

// Round 7
// 100.797 us; speedup vs baseline: 16.6617x; 1.1801x over previous
//
#include <hip/hip_runtime.h>
#include <math.h>

#define T_SEQ 2048
#define HID   1024
#define NH    16
#define HD    64
#define NT    (T_SEQ / 64)

typedef __attribute__((ext_vector_type(8))) __bf16 bf16x8;
typedef __attribute__((ext_vector_type(4))) float  f32x4;
typedef __attribute__((ext_vector_type(8))) unsigned short u16x8;

#define GPTR(p) (const __attribute__((address_space(1))) void*)(p)
#define SPTR(p) (__attribute__((address_space(3))) void*)(p)

__device__ __forceinline__ unsigned short f2bf(float x) {
    unsigned u = __float_as_uint(x);
    u = (u + 0x7FFF + ((u >> 16) & 1)) >> 16;   // RNE
    return (unsigned short)u;
}
__device__ __forceinline__ float bf2f(unsigned short u) {
    return __uint_as_float((unsigned)u << 16);
}

// ---------------- f32 -> bf16 conversion (5 segments) ----------------
__global__ __launch_bounds__(256) void f2bf_multi(
    const float* __restrict__ p0, const float* __restrict__ p1,
    const float* __restrict__ p2, const float* __restrict__ p3,
    const float* __restrict__ p4,
    unsigned short* o0, unsigned short* o1, unsigned short* o2,
    unsigned short* o3, unsigned short* o4,
    int n0, int n1, int n2, int n3, int n4)
{
    const float* in; unsigned short* out; int n;
    switch (blockIdx.y) {
        case 0: in = p0; out = o0; n = n0; break;
        case 1: in = p1; out = o1; n = n1; break;
        case 2: in = p2; out = o2; n = n2; break;
        case 3: in = p3; out = o3; n = n3; break;
        default: in = p4; out = o4; n = n4; break;
    }
    const int stride = gridDim.x * blockDim.x;
    for (int i = blockIdx.x * blockDim.x + threadIdx.x; i < n / 4; i += stride) {
        float4 v = reinterpret_cast<const float4*>(in)[i];
        ushort4 r;
        r.x = f2bf(v.x); r.y = f2bf(v.y); r.z = f2bf(v.z); r.w = f2bf(v.w);
        reinterpret_cast<ushort4*>(out)[i] = r;
    }
}

// ---------------- bf16 MFMA GEMM, templated tile: C = A @ W^T ----------------
// 4 waves in 2x2; wave sub-tile (BM/2)x(BN/2); FM=BM/32, FN=BN/32 fragments.
// EMODE 0 (qkv): z=0 -> qb [T][HID]*0.125; z=1 -> kb [NH][T][64]; z=2 -> vt [NH][64][T].
// EMODE 1: f32 C store. Grid pre-swizzled for XCD locality (nwg%8==0 required).
template<int BM, int BN, int EMODE>
__global__ __launch_bounds__(256) void gemm_mfma_bt(
    const unsigned short* __restrict__ A,
    const unsigned short* __restrict__ W0, const unsigned short* __restrict__ W1,
    const unsigned short* __restrict__ W2,
    float* __restrict__ C,
    unsigned short* __restrict__ qb, unsigned short* __restrict__ kb,
    unsigned short* __restrict__ vt,
    int M, int N, int K)
{
    const unsigned short* W = blockIdx.z == 0 ? W0 : (blockIdx.z == 1 ? W1 : W2);

    __shared__ unsigned short Als[BM * 64];
    __shared__ unsigned short Bls[BN * 64];

    // XCD-aware bijective swizzle of the 2D grid (nwg % 8 == 0)
    const int gx  = gridDim.x;
    const int nwg = gx * gridDim.y;
    const int lin = blockIdx.y * gx + blockIdx.x;
    const int cpx = nwg >> 3;
    const int sw  = (lin & 7) * cpx + (lin >> 3);
    const int bx  = sw % gx;
    const int by  = sw / gx;

    const int tid = threadIdx.x;
    const int w   = tid >> 6;
    const int l   = tid & 63;
    const int bm  = by * BM;
    const int bn  = bx * BN;
    const int wm  = (w >> 1) * (BM / 2);
    const int wn  = (w & 1) * (BN / 2);
    constexpr int FM = BM / 32;
    constexpr int FN = BN / 32;

    f32x4 acc[FM][FN];
    #pragma unroll
    for (int m = 0; m < FM; ++m)
        #pragma unroll
        for (int n = 0; n < FN; ++n) acc[m][n] = (f32x4){0.f, 0.f, 0.f, 0.f};

    const int frow = l & 15;
    const int kgrp = (l >> 4) * 16;
    const int swz  = (l & 7) << 4;

    const unsigned short* Ag = A + (size_t)bm * K;
    const unsigned short* Wg = W + (size_t)bn * K;

    for (int k0 = 0; k0 < K; k0 += 64) {
        __syncthreads();
        #pragma unroll
        for (int j = 0; j < FM; ++j) {
            const int idxb = j * 4096 + tid * 16;
            const int row  = idxb >> 7;
            const int kbyt = idxb & 127;
            const int col  = (kbyt ^ ((row & 7) << 4)) >> 1;
            const int ldsh = (j * 4096 + w * 1024) >> 1;
            __builtin_amdgcn_global_load_lds(
                GPTR(Ag + (size_t)row * K + k0 + col), SPTR(Als + ldsh), 16, 0, 0);
        }
        #pragma unroll
        for (int j = 0; j < FN; ++j) {
            const int idxb = j * 4096 + tid * 16;
            const int row  = idxb >> 7;
            const int kbyt = idxb & 127;
            const int col  = (kbyt ^ ((row & 7) << 4)) >> 1;
            const int ldsh = (j * 4096 + w * 1024) >> 1;
            __builtin_amdgcn_global_load_lds(
                GPTR(Wg + (size_t)row * K + k0 + col), SPTR(Bls + ldsh), 16, 0, 0);
        }
        __syncthreads();

        #pragma unroll
        for (int ks = 0; ks < 2; ++ks) {
            bf16x8 af[FM], bfr[FN];
            #pragma unroll
            for (int m = 0; m < FM; ++m) {
                const int off = (wm + m * 16 + frow) * 128 + ((ks * 64 + kgrp) ^ swz);
                af[m] = *reinterpret_cast<const bf16x8*>((const char*)Als + off);
            }
            #pragma unroll
            for (int n = 0; n < FN; ++n) {
                const int off = (wn + n * 16 + frow) * 128 + ((ks * 64 + kgrp) ^ swz);
                bfr[n] = *reinterpret_cast<const bf16x8*>((const char*)Bls + off);
            }
            #pragma unroll
            for (int m = 0; m < FM; ++m)
                #pragma unroll
                for (int n = 0; n < FN; ++n)
                    acc[m][n] = __builtin_amdgcn_mfma_f32_16x16x32_bf16(
                        af[m], bfr[n], acc[m][n], 0, 0, 0);
        }
    }

    const int r0 = (l >> 4) * 4;
    const int cc = l & 15;
    if (EMODE == 1) {
        #pragma unroll
        for (int m = 0; m < FM; ++m)
            #pragma unroll
            for (int n = 0; n < FN; ++n) {
                float* cp = C + (size_t)(bm + wm + m * 16 + r0) * N + bn + wn + n * 16 + cc;
                #pragma unroll
                for (int r = 0; r < 4; ++r) cp[(size_t)r * N] = acc[m][n][r];
            }
    } else {
        const int z = blockIdx.z;
        if (z == 0) {
            #pragma unroll
            for (int m = 0; m < FM; ++m) {
                const int t0 = bm + wm + m * 16 + r0;
                #pragma unroll
                for (int n = 0; n < FN; ++n) {
                    const int col = bn + wn + n * 16 + cc;
                    #pragma unroll
                    for (int r = 0; r < 4; ++r)
                        qb[(size_t)(t0 + r) * HID + col] = f2bf(acc[m][n][r] * 0.125f);
                }
            }
        } else if (z == 1) {
            #pragma unroll
            for (int m = 0; m < FM; ++m) {
                const int t0 = bm + wm + m * 16 + r0;
                #pragma unroll
                for (int n = 0; n < FN; ++n) {
                    const int col = bn + wn + n * 16 + cc;
                    const int hh  = col >> 6;
                    const int d   = col & 63;
                    #pragma unroll
                    for (int r = 0; r < 4; ++r)
                        kb[(size_t)hh * T_SEQ * HD + (size_t)(t0 + r) * HD + d] =
                            f2bf(acc[m][n][r]);
                }
            }
        } else {
            #pragma unroll
            for (int m = 0; m < FM; ++m) {
                const int t0 = bm + wm + m * 16 + r0;
                #pragma unroll
                for (int n = 0; n < FN; ++n) {
                    const int col = bn + wn + n * 16 + cc;
                    const int hh  = col >> 6;
                    const int d   = col & 63;
                    ushort4 pk;
                    pk.x = f2bf(acc[m][n][0]); pk.y = f2bf(acc[m][n][1]);
                    pk.z = f2bf(acc[m][n][2]); pk.w = f2bf(acc[m][n][3]);
                    *reinterpret_cast<ushort4*>(
                        vt + (size_t)hh * HD * T_SEQ + (size_t)d * T_SEQ + t0) = pk;
                }
            }
        }
    }
}

// ---------------- f = log_sigmoid(hs @ Wf^T + bf), [T,NH] ----------------
__global__ __launch_bounds__(256) void fproj(const float* __restrict__ hs,
                                             const float* __restrict__ Wf,
                                             const float* __restrict__ bf,
                                             float* __restrict__ f)
{
    const int t  = blockIdx.x;
    const int h  = threadIdx.x >> 4;
    const int sl = threadIdx.x & 15;
    const float4* hrow = reinterpret_cast<const float4*>(hs + (size_t)t * HID);
    const float4* wrow = reinterpret_cast<const float4*>(Wf + (size_t)h * HID);
    float s = 0.f;
    #pragma unroll
    for (int i = 0; i < 16; ++i) {
        float4 a = hrow[sl + i * 16];
        float4 b = wrow[sl + i * 16];
        s += a.x * b.x + a.y * b.y + a.z * b.z + a.w * b.w;
    }
    s += __shfl_xor(s, 1);
    s += __shfl_xor(s, 2);
    s += __shfl_xor(s, 4);
    s += __shfl_xor(s, 8);
    if (sl == 0) {
        float x = s + bf[h];
        f[t * NH + h] = (x >= 0.f) ? -log1pf(expf(-x)) : (x - log1pf(expf(x)));
    }
}

// ---------------- fwd/bwd inclusive cumsum, 4 waves x 512-elem segments ----------------
__global__ __launch_bounds__(256) void cumsum_f(const float* __restrict__ f,
                                                float* __restrict__ gcf,
                                                float* __restrict__ gcb)
{
    const int h   = blockIdx.x;
    const int rev = blockIdx.y;
    float* out = rev ? gcb : gcf;
    const int wv   = threadIdx.x >> 6;
    const int lane = threadIdx.x & 63;

    __shared__ float wtot[4];

    float vals[8];
    float run = 0.f;
    #pragma unroll
    for (int c = 0; c < 8; ++c) {
        const int p = wv * 512 + c * 64 + lane;
        const int t = rev ? (T_SEQ - 1 - p) : p;
        float x = f[t * NH + h];
        #pragma unroll
        for (int off = 1; off < 64; off <<= 1) {
            float y = __shfl_up(x, off);
            if (lane >= off) x += y;
        }
        vals[c] = run + x;
        run += __shfl(x, 63);
    }
    if (lane == 0) wtot[wv] = run;
    __syncthreads();
    float prefix = 0.f;
    #pragma unroll
    for (int i = 0; i < 4; ++i) prefix += (i < wv) ? wtot[i] : 0.f;
    #pragma unroll
    for (int c = 0; c < 8; ++c) {
        const int p = wv * 512 + c * 64 + lane;
        const int t = rev ? (T_SEQ - 1 - p) : p;
        out[t * NH + h] = vals[c] + prefix;
    }
}

// ---------------- per-head max ||k_row||_2 from bf16 kb [NH][T][64] ----------------
__global__ __launch_bounds__(256) void knorms(const unsigned short* __restrict__ kb,
                                              float* __restrict__ knmax)
{
    const int h    = blockIdx.x;
    const int tid  = threadIdx.x;
    const int wv   = tid >> 6;
    const int lane = tid & 63;
    __shared__ float wmax[4];
    float mx = 0.f;
    for (int t = tid; t < T_SEQ; t += 256) {
        const u16x8* kr = reinterpret_cast<const u16x8*>(
            kb + (size_t)h * T_SEQ * HD + (size_t)t * HD);
        float s = 0.f;
        #pragma unroll
        for (int i = 0; i < 8; ++i) {
            u16x8 v8 = kr[i];
            #pragma unroll
            for (int j = 0; j < 8; ++j) { float x = bf2f(v8[j]); s += x * x; }
        }
        mx = fmaxf(mx, s);
    }
    #pragma unroll
    for (int off = 32; off > 0; off >>= 1) mx = fmaxf(mx, __shfl_xor(mx, off));
    if (lane == 0) wmax[wv] = mx;
    __syncthreads();
    if (tid == 0) {
        float m = fmaxf(fmaxf(wmax[0], wmax[1]), fmaxf(wmax[2], wmax[3]));
        knmax[h] = sqrtf(m);
    }
}

// ---------------- MFMA flash attention, bf16-native inputs ----------------
__global__ __launch_bounds__(256) void attn_flash(
    const unsigned short* __restrict__ qb, const unsigned short* __restrict__ kg,
    const unsigned short* __restrict__ vg,
    const float* __restrict__ gcf, const float* __restrict__ gcb,
    const float* __restrict__ knmax,
    unsigned short* __restrict__ ocat)
{
    const int dir = blockIdx.z;
    const float* gc = dir ? gcb : gcf;
    const int h   = blockIdx.y;
    const int qt  = blockIdx.x;
    const int q0  = qt * 64;
    const int tid = threadIdx.x;
    const int w   = tid >> 6;
    const int l   = tid & 63;
    const int lm  = l & 15;
    const int lg  = l >> 4;
    const int swz = (l & 7) << 4;

    __shared__ unsigned short Kls[64 * 64];
    __shared__ unsigned short Vls[64 * 64];
    __shared__ unsigned short Pls[64 * 64];
    __shared__ float gks[64];
    __shared__ float qbs[64];

    const size_t kgbase = (size_t)h * T_SEQ * HD;
    const size_t vgbase = (size_t)h * HD * T_SEQ;

    const int qrow_a = q0 + 16 * w + lm;
    bf16x8 aq[2];
    aq[0] = *reinterpret_cast<const bf16x8*>(qb + (size_t)qrow_a * HID + h * HD + lg * 8);
    aq[1] = *reinterpret_cast<const bf16x8*>(qb + (size_t)qrow_a * HID + h * HD + 32 + lg * 8);
    float qn2 = 0.f;
    #pragma unroll
    for (int ks = 0; ks < 2; ++ks) {
        u16x8 uv = *reinterpret_cast<const u16x8*>(&aq[ks]);
        #pragma unroll
        for (int j = 0; j < 8; ++j) { float x = bf2f(uv[j]); qn2 += x * x; }
    }
    qn2 += __shfl_xor(qn2, 16);
    qn2 += __shfl_xor(qn2, 32);
    if (lg == 0) qbs[16 * w + lm] = sqrtf(qn2) * knmax[h];

    float gq_r[4];
    #pragma unroll
    for (int reg = 0; reg < 4; ++reg)
        gq_r[reg] = gc[(q0 + 16 * w + lg * 4 + reg) * NH + h];

    float mrun[4], lrun[4];
    #pragma unroll
    for (int reg = 0; reg < 4; ++reg) { mrun[reg] = -1e30f; lrun[reg] = 0.f; }
    f32x4 acc[4];
    #pragma unroll
    for (int db = 0; db < 4; ++db) acc[db] = (f32x4){0.f, 0.f, 0.f, 0.f};

    const int stp = dir ? 1 : -1;
    for (int kt = qt; kt >= 0 && kt < NT; kt += stp) {
        const int k0 = kt * 64;

        #pragma unroll
        for (int j = 0; j < 2; ++j) {
            const int idxb = j * 4096 + tid * 16;
            const int row  = idxb >> 7;
            const int kbyt = idxb & 127;
            const int scol = (kbyt ^ ((row & 7) << 4)) >> 1;
            const int ldsh = (j * 4096 + w * 1024) >> 1;
            __builtin_amdgcn_global_load_lds(
                GPTR(kg + kgbase + (size_t)(k0 + row) * HD + scol),
                SPTR(Kls + ldsh), 16, 0, 0);
            __builtin_amdgcn_global_load_lds(
                GPTR(vg + vgbase + (size_t)row * T_SEQ + k0 + scol),
                SPTR(Vls + ldsh), 16, 0, 0);
        }
        if (w == 0)
            __builtin_amdgcn_global_load_lds(
                GPTR(gc + (size_t)(k0 + l) * NH + h), SPTR(gks), 4, 0, 0);
        __syncthreads();

        f32x4 s[4];
        #pragma unroll
        for (int cb = 0; cb < 4; ++cb) {
            bf16x8 b0 = *reinterpret_cast<const bf16x8*>(
                (char*)Kls + (cb * 16 + lm) * 128 + ((lg * 16) ^ swz));
            bf16x8 b1 = *reinterpret_cast<const bf16x8*>(
                (char*)Kls + (cb * 16 + lm) * 128 + ((64 + lg * 16) ^ swz));
            f32x4 z = (f32x4){0.f, 0.f, 0.f, 0.f};
            z = __builtin_amdgcn_mfma_f32_16x16x32_bf16(aq[0], b0, z, 0, 0, 0);
            s[cb] = __builtin_amdgcn_mfma_f32_16x16x32_bf16(aq[1], b1, z, 0, 0, 0);
        }

        float gk_c[4];
        #pragma unroll
        for (int cb = 0; cb < 4; ++cb) gk_c[cb] = gks[cb * 16 + lm];
        float sv[4][4];
        const bool diag = (kt == qt);
        #pragma unroll
        for (int cb = 0; cb < 4; ++cb)
            #pragma unroll
            for (int reg = 0; reg < 4; ++reg) {
                float x = s[cb][reg] + gq_r[reg] - gk_c[cb];
                if (diag) {
                    const int c_loc = cb * 16 + lm;
                    const int r_loc = 16 * w + lg * 4 + reg;
                    const bool valid = dir ? (c_loc >= r_loc) : (c_loc <= r_loc);
                    x = valid ? x : -1e30f;
                }
                sv[cb][reg] = x;
            }

        float corr[4], mnew[4];
        #pragma unroll
        for (int reg = 0; reg < 4; ++reg) {
            float rm = fmaxf(fmaxf(sv[0][reg], sv[1][reg]), fmaxf(sv[2][reg], sv[3][reg]));
            rm = fmaxf(rm, __shfl_xor(rm, 1));
            rm = fmaxf(rm, __shfl_xor(rm, 2));
            rm = fmaxf(rm, __shfl_xor(rm, 4));
            rm = fmaxf(rm, __shfl_xor(rm, 8));
            mnew[reg] = fmaxf(mrun[reg], rm);
            corr[reg] = __expf(mrun[reg] - mnew[reg]);
            mrun[reg] = mnew[reg];
        }
        float psum[4] = {0.f, 0.f, 0.f, 0.f};
        #pragma unroll
        for (int cb = 0; cb < 4; ++cb)
            #pragma unroll
            for (int reg = 0; reg < 4; ++reg) {
                const float p = __expf(sv[cb][reg] - mnew[reg]);
                psum[reg] += p;
                const int r_loc = 16 * w + lg * 4 + reg;
                *reinterpret_cast<unsigned short*>(
                    (char*)Pls + r_loc * 128 + ((cb * 32 + lm * 2) ^ ((r_loc & 7) << 4))) = f2bf(p);
            }
        #pragma unroll
        for (int reg = 0; reg < 4; ++reg) {
            float ps = psum[reg];
            ps += __shfl_xor(ps, 1);
            ps += __shfl_xor(ps, 2);
            ps += __shfl_xor(ps, 4);
            ps += __shfl_xor(ps, 8);
            lrun[reg] = lrun[reg] * corr[reg] + ps;
        }
        #pragma unroll
        for (int db = 0; db < 4; ++db)
            #pragma unroll
            for (int reg = 0; reg < 4; ++reg) acc[db][reg] *= corr[reg];

        bf16x8 ap[2];
        #pragma unroll
        for (int ks = 0; ks < 2; ++ks)
            ap[ks] = *reinterpret_cast<const bf16x8*>(
                (char*)Pls + (16 * w + lm) * 128 + ((ks * 64 + lg * 16) ^ swz));
        #pragma unroll
        for (int db = 0; db < 4; ++db) {
            bf16x8 bv0 = *reinterpret_cast<const bf16x8*>(
                (char*)Vls + (db * 16 + lm) * 128 + ((lg * 16) ^ swz));
            bf16x8 bv1 = *reinterpret_cast<const bf16x8*>(
                (char*)Vls + (db * 16 + lm) * 128 + ((64 + lg * 16) ^ swz));
            acc[db] = __builtin_amdgcn_mfma_f32_16x16x32_bf16(ap[0], bv0, acc[db], 0, 0, 0);
            acc[db] = __builtin_amdgcn_mfma_f32_16x16x32_bf16(ap[1], bv1, acc[db], 0, 0, 0);
        }

        const int nkt = kt + stp;
        if (nkt >= 0 && nkt < NT) {
            const float gkedge = dir ? gc[(nkt * 64) * NH + h]
                                     : gc[(nkt * 64 + 63) * NH + h];
            int pred = 0;
            #pragma unroll
            for (int reg = 0; reg < 4; ++reg) {
                const float qbv = qbs[16 * w + lg * 4 + reg];
                pred |= (qbv + gq_r[reg] - gkedge) >= (mrun[reg] - 15.f);
            }
            if (!__syncthreads_or(pred)) break;
        }
    }

    float inv[4];
    #pragma unroll
    for (int reg = 0; reg < 4; ++reg) inv[reg] = 1.f / lrun[reg];
    #pragma unroll
    for (int db = 0; db < 4; ++db)
        #pragma unroll
        for (int reg = 0; reg < 4; ++reg) {
            const int row = q0 + 16 * w + lg * 4 + reg;
            const int col = db * 16 + lm;
            ocat[(size_t)row * (2 * HID) + dir * HID + h * HD + col] =
                f2bf(acc[db][reg] * inv[reg]);
        }
}

// ---------------- launch ----------------
extern "C" void kernel_launch(void* const* d_in, const int* in_sizes, int n_in,
                              void* d_out, int out_size, void* d_ws, size_t ws_size,
                              hipStream_t stream)
{
    (void)in_sizes; (void)n_in; (void)out_size; (void)ws_size;
    const float* hs = (const float*)d_in[0];
    const float* Wq = (const float*)d_in[1];
    const float* Wk = (const float*)d_in[2];
    const float* Wv = (const float*)d_in[3];
    const float* Wf = (const float*)d_in[4];
    const float* bf = (const float*)d_in[5];
    const float* Wo = (const float*)d_in[6];
    float* out = (float*)d_out;

    float* ws    = (float*)d_ws;
    float* f     = ws;
    float* gcf   = f   + (size_t)T_SEQ * NH;
    float* gcb   = gcf + (size_t)T_SEQ * NH;
    float* knmax = gcb + (size_t)T_SEQ * NH;
    unsigned short* hsb  = (unsigned short*)(knmax + 64);
    unsigned short* wqb  = hsb + (size_t)T_SEQ * HID;
    unsigned short* wkb  = wqb + (size_t)HID * HID;
    unsigned short* wvb  = wkb + (size_t)HID * HID;
    unsigned short* wob  = wvb + (size_t)HID * HID;
    unsigned short* qb   = wob + (size_t)HID * 2 * HID;
    unsigned short* kb   = qb  + (size_t)T_SEQ * HID;
    unsigned short* vt   = kb  + (size_t)T_SEQ * HID;
    unsigned short* ocat = vt  + (size_t)T_SEQ * HID;

    f2bf_multi<<<dim3(256, 5), 256, 0, stream>>>(
        hs, Wq, Wk, Wv, Wo, hsb, wqb, wkb, wvb, wob,
        T_SEQ * HID, HID * HID, HID * HID, HID * HID, HID * 2 * HID);

    // qkv projections: 128x64 tile -> 16x16x3 = 768 blocks (3/CU)
    gemm_mfma_bt<128, 64, 0><<<dim3(HID / 64, T_SEQ / 128, 3), 256, 0, stream>>>(
        hsb, wqb, wkb, wvb, nullptr, qb, kb, vt, T_SEQ, HID, HID);

    fproj<<<T_SEQ, 256, 0, stream>>>(hs, Wf, bf, f);
    cumsum_f<<<dim3(NH, 2), 256, 0, stream>>>(f, gcf, gcb);
    knorms<<<NH, 256, 0, stream>>>(kb, knmax);

    attn_flash<<<dim3(NT, NH, 2), 256, 0, stream>>>(qb, kb, vt, gcf, gcb, knmax, ocat);

    // out = ocat @ Wo^T: 64x64 tile -> 16x32 = 512 blocks (2/CU)
    gemm_mfma_bt<64, 64, 1><<<dim3(HID / 64, T_SEQ / 64, 1), 256, 0, stream>>>(
        ocat, wob, nullptr, nullptr, out, nullptr, nullptr, nullptr,
        T_SEQ, HID, 2 * HID);
}

// Round 8
// 93.352 us; speedup vs baseline: 17.9906x; 1.0798x over previous
//
#include <hip/hip_runtime.h>
#include <math.h>

#define T_SEQ 2048
#define HID   1024
#define NH    16
#define HD    64
#define NT    (T_SEQ / 64)

typedef __attribute__((ext_vector_type(8))) __bf16 bf16x8;
typedef __attribute__((ext_vector_type(4))) float  f32x4;
typedef __attribute__((ext_vector_type(8))) unsigned short u16x8;

#define GPTR(p) (const __attribute__((address_space(1))) void*)(p)
#define SPTR(p) (__attribute__((address_space(3))) void*)(p)

__device__ __forceinline__ unsigned short f2bf(float x) {
    unsigned u = __float_as_uint(x);
    u = (u + 0x7FFF + ((u >> 16) & 1)) >> 16;   // RNE
    return (unsigned short)u;
}
__device__ __forceinline__ float bf2f(unsigned short u) {
    return __uint_as_float((unsigned)u << 16);
}

// ---------------- prep1: f32->bf16 conversions (y<5) + fproj (y==5) ----------------
__global__ __launch_bounds__(256) void prep1(
    const float* __restrict__ hs,
    const float* __restrict__ Wq, const float* __restrict__ Wk,
    const float* __restrict__ Wv, const float* __restrict__ Wo,
    const float* __restrict__ Wf, const float* __restrict__ bfv,
    unsigned short* __restrict__ hsb, unsigned short* __restrict__ wqb,
    unsigned short* __restrict__ wkb, unsigned short* __restrict__ wvb,
    unsigned short* __restrict__ wob, float* __restrict__ f)
{
    const int y = blockIdx.y;
    if (y < 5) {
        const float* in; unsigned short* out; int n;
        switch (y) {
            case 0: in = hs; out = hsb; n = T_SEQ * HID; break;
            case 1: in = Wq; out = wqb; n = HID * HID;   break;
            case 2: in = Wk; out = wkb; n = HID * HID;   break;
            case 3: in = Wv; out = wvb; n = HID * HID;   break;
            default: in = Wo; out = wob; n = HID * 2 * HID; break;
        }
        const int stride = gridDim.x * blockDim.x;
        for (int i = blockIdx.x * blockDim.x + threadIdx.x; i < n / 4; i += stride) {
            float4 v = reinterpret_cast<const float4*>(in)[i];
            ushort4 r;
            r.x = f2bf(v.x); r.y = f2bf(v.y); r.z = f2bf(v.z); r.w = f2bf(v.w);
            reinterpret_cast<ushort4*>(out)[i] = r;
        }
    } else {
        // fproj: 16 lanes per head
        const int t  = blockIdx.x;
        const int h  = threadIdx.x >> 4;
        const int sl = threadIdx.x & 15;
        const float4* hrow = reinterpret_cast<const float4*>(hs + (size_t)t * HID);
        const float4* wrow = reinterpret_cast<const float4*>(Wf + (size_t)h * HID);
        float s = 0.f;
        #pragma unroll
        for (int i = 0; i < 16; ++i) {
            float4 a = hrow[sl + i * 16];
            float4 b = wrow[sl + i * 16];
            s += a.x * b.x + a.y * b.y + a.z * b.z + a.w * b.w;
        }
        s += __shfl_xor(s, 1);
        s += __shfl_xor(s, 2);
        s += __shfl_xor(s, 4);
        s += __shfl_xor(s, 8);
        if (sl == 0) {
            float x = s + bfv[h];
            f[t * NH + h] = (x >= 0.f) ? -log1pf(expf(-x)) : (x - log1pf(expf(x)));
        }
    }
}

// ---------------- stage one operand K-tile into LDS (async, swizzled src) ----------------
template<int FR>
__device__ __forceinline__ void stage_tile(const unsigned short* __restrict__ G, int K,
                                           int k0, unsigned short* lds, int tid, int w)
{
    #pragma unroll
    for (int j = 0; j < FR; ++j) {
        const int idxb = j * 4096 + tid * 16;
        const int row  = idxb >> 7;
        const int kbyt = idxb & 127;
        const int col  = (kbyt ^ ((row & 7) << 4)) >> 1;
        const int ldsh = (j * 4096 + w * 1024) >> 1;
        __builtin_amdgcn_global_load_lds(
            GPTR(G + (size_t)row * K + k0 + col), SPTR(lds + ldsh), 16, 0, 0);
    }
}

// ---------------- bf16 MFMA GEMM, 2-phase double-buffered ----------------
// EMODE 0 (qkv): z=0 -> qb [T][HID]*0.125; z=1 -> kb [NH][T][64]; z=2 -> vt [NH][64][T].
// EMODE 1: f32 C store. Grid pre-swizzled for XCD locality (nwg%8==0 required).
template<int BM, int BN, int EMODE>
__global__ __launch_bounds__(256) void gemm_mfma_bt(
    const unsigned short* __restrict__ A,
    const unsigned short* __restrict__ W0, const unsigned short* __restrict__ W1,
    const unsigned short* __restrict__ W2,
    float* __restrict__ C,
    unsigned short* __restrict__ qb, unsigned short* __restrict__ kb,
    unsigned short* __restrict__ vt,
    int M, int N, int K)
{
    const unsigned short* W = blockIdx.z == 0 ? W0 : (blockIdx.z == 1 ? W1 : W2);

    __shared__ unsigned short Als[2][BM * 64];
    __shared__ unsigned short Bls[2][BN * 64];

    // XCD-aware bijective swizzle (nwg % 8 == 0)
    const int gx  = gridDim.x;
    const int nwg = gx * gridDim.y;
    const int lin = blockIdx.y * gx + blockIdx.x;
    const int cpx = nwg >> 3;
    const int sw  = (lin & 7) * cpx + (lin >> 3);
    const int bx  = sw % gx;
    const int by  = sw / gx;

    const int tid = threadIdx.x;
    const int w   = tid >> 6;
    const int l   = tid & 63;
    const int bm  = by * BM;
    const int bn  = bx * BN;
    const int wm  = (w >> 1) * (BM / 2);
    const int wn  = (w & 1) * (BN / 2);
    constexpr int FM = BM / 32;
    constexpr int FN = BN / 32;

    f32x4 acc[FM][FN];
    #pragma unroll
    for (int m = 0; m < FM; ++m)
        #pragma unroll
        for (int n = 0; n < FN; ++n) acc[m][n] = (f32x4){0.f, 0.f, 0.f, 0.f};

    const int frow = l & 15;
    const int kgrp = (l >> 4) * 16;
    const int swz  = (l & 7) << 4;

    const unsigned short* Ag = A + (size_t)bm * K;
    const unsigned short* Wg = W + (size_t)bn * K;

    const int NIT = K >> 6;
    stage_tile<FM>(Ag, K, 0, Als[0], tid, w);
    stage_tile<FN>(Wg, K, 0, Bls[0], tid, w);
    __syncthreads();           // vmcnt drained -> buf0 ready

    int cur = 0;
    for (int it = 0; it < NIT; ++it) {
        if (it + 1 < NIT) {    // issue next-tile loads before compute (overlap)
            stage_tile<FM>(Ag, K, (it + 1) * 64, Als[cur ^ 1], tid, w);
            stage_tile<FN>(Wg, K, (it + 1) * 64, Bls[cur ^ 1], tid, w);
        }
        const unsigned short* Ap = Als[cur];
        const unsigned short* Bp = Bls[cur];
        #pragma unroll
        for (int ks = 0; ks < 2; ++ks) {
            bf16x8 af[FM], bfr[FN];
            #pragma unroll
            for (int m = 0; m < FM; ++m) {
                const int off = (wm + m * 16 + frow) * 128 + ((ks * 64 + kgrp) ^ swz);
                af[m] = *reinterpret_cast<const bf16x8*>((const char*)Ap + off);
            }
            #pragma unroll
            for (int n = 0; n < FN; ++n) {
                const int off = (wn + n * 16 + frow) * 128 + ((ks * 64 + kgrp) ^ swz);
                bfr[n] = *reinterpret_cast<const bf16x8*>((const char*)Bp + off);
            }
            #pragma unroll
            for (int m = 0; m < FM; ++m)
                #pragma unroll
                for (int n = 0; n < FN; ++n)
                    acc[m][n] = __builtin_amdgcn_mfma_f32_16x16x32_bf16(
                        af[m], bfr[n], acc[m][n], 0, 0, 0);
        }
        __syncthreads();       // drains vmcnt: next buffer ready; cur reads done
        cur ^= 1;
    }

    const int r0 = (l >> 4) * 4;
    const int cc = l & 15;
    if (EMODE == 1) {
        #pragma unroll
        for (int m = 0; m < FM; ++m)
            #pragma unroll
            for (int n = 0; n < FN; ++n) {
                float* cp = C + (size_t)(bm + wm + m * 16 + r0) * N + bn + wn + n * 16 + cc;
                #pragma unroll
                for (int r = 0; r < 4; ++r) cp[(size_t)r * N] = acc[m][n][r];
            }
    } else {
        const int z = blockIdx.z;
        if (z == 0) {
            #pragma unroll
            for (int m = 0; m < FM; ++m) {
                const int t0 = bm + wm + m * 16 + r0;
                #pragma unroll
                for (int n = 0; n < FN; ++n) {
                    const int col = bn + wn + n * 16 + cc;
                    #pragma unroll
                    for (int r = 0; r < 4; ++r)
                        qb[(size_t)(t0 + r) * HID + col] = f2bf(acc[m][n][r] * 0.125f);
                }
            }
        } else if (z == 1) {
            #pragma unroll
            for (int m = 0; m < FM; ++m) {
                const int t0 = bm + wm + m * 16 + r0;
                #pragma unroll
                for (int n = 0; n < FN; ++n) {
                    const int col = bn + wn + n * 16 + cc;
                    const int hh  = col >> 6;
                    const int d   = col & 63;
                    #pragma unroll
                    for (int r = 0; r < 4; ++r)
                        kb[(size_t)hh * T_SEQ * HD + (size_t)(t0 + r) * HD + d] =
                            f2bf(acc[m][n][r]);
                }
            }
        } else {
            #pragma unroll
            for (int m = 0; m < FM; ++m) {
                const int t0 = bm + wm + m * 16 + r0;
                #pragma unroll
                for (int n = 0; n < FN; ++n) {
                    const int col = bn + wn + n * 16 + cc;
                    const int hh  = col >> 6;
                    const int d   = col & 63;
                    ushort4 pk;
                    pk.x = f2bf(acc[m][n][0]); pk.y = f2bf(acc[m][n][1]);
                    pk.z = f2bf(acc[m][n][2]); pk.w = f2bf(acc[m][n][3]);
                    *reinterpret_cast<ushort4*>(
                        vt + (size_t)hh * HD * T_SEQ + (size_t)d * T_SEQ + t0) = pk;
                }
            }
        }
    }
}

// ---------------- prep2: cumsum (blocks 0..31) + knorms (blocks 32..47) ----------------
__global__ __launch_bounds__(256) void prep2(const float* __restrict__ f,
                                             float* __restrict__ gcf,
                                             float* __restrict__ gcb,
                                             const unsigned short* __restrict__ kb,
                                             float* __restrict__ knmax)
{
    const int bid = blockIdx.x;
    if (bid < 32) {
        const int h   = bid >> 1;
        const int rev = bid & 1;
        float* out = rev ? gcb : gcf;
        const int wv   = threadIdx.x >> 6;
        const int lane = threadIdx.x & 63;
        __shared__ float wtot[4];
        float vals[8];
        float run = 0.f;
        #pragma unroll
        for (int c = 0; c < 8; ++c) {
            const int p = wv * 512 + c * 64 + lane;
            const int t = rev ? (T_SEQ - 1 - p) : p;
            float x = f[t * NH + h];
            #pragma unroll
            for (int off = 1; off < 64; off <<= 1) {
                float y = __shfl_up(x, off);
                if (lane >= off) x += y;
            }
            vals[c] = run + x;
            run += __shfl(x, 63);
        }
        if (lane == 0) wtot[wv] = run;
        __syncthreads();
        float prefix = 0.f;
        #pragma unroll
        for (int i = 0; i < 4; ++i) prefix += (i < wv) ? wtot[i] : 0.f;
        #pragma unroll
        for (int c = 0; c < 8; ++c) {
            const int p = wv * 512 + c * 64 + lane;
            const int t = rev ? (T_SEQ - 1 - p) : p;
            out[t * NH + h] = vals[c] + prefix;
        }
    } else {
        const int h    = bid - 32;
        const int tid  = threadIdx.x;
        const int wv   = tid >> 6;
        const int lane = tid & 63;
        __shared__ float wmax[4];
        float mx = 0.f;
        for (int t = tid; t < T_SEQ; t += 256) {
            const u16x8* kr = reinterpret_cast<const u16x8*>(
                kb + (size_t)h * T_SEQ * HD + (size_t)t * HD);
            float s = 0.f;
            #pragma unroll
            for (int i = 0; i < 8; ++i) {
                u16x8 v8 = kr[i];
                #pragma unroll
                for (int j = 0; j < 8; ++j) { float x = bf2f(v8[j]); s += x * x; }
            }
            mx = fmaxf(mx, s);
        }
        #pragma unroll
        for (int off = 32; off > 0; off >>= 1) mx = fmaxf(mx, __shfl_xor(mx, off));
        if (lane == 0) wmax[wv] = mx;
        __syncthreads();
        if (tid == 0) {
            float m = fmaxf(fmaxf(wmax[0], wmax[1]), fmaxf(wmax[2], wmax[3]));
            knmax[h] = sqrtf(m);
        }
    }
}

// ---------------- MFMA flash attention, bf16-native inputs ----------------
__global__ __launch_bounds__(256) void attn_flash(
    const unsigned short* __restrict__ qb, const unsigned short* __restrict__ kg,
    const unsigned short* __restrict__ vg,
    const float* __restrict__ gcf, const float* __restrict__ gcb,
    const float* __restrict__ knmax,
    unsigned short* __restrict__ ocat)
{
    const int dir = blockIdx.z;
    const float* gc = dir ? gcb : gcf;
    const int h   = blockIdx.y;
    const int qt  = blockIdx.x;
    const int q0  = qt * 64;
    const int tid = threadIdx.x;
    const int w   = tid >> 6;
    const int l   = tid & 63;
    const int lm  = l & 15;
    const int lg  = l >> 4;
    const int swz = (l & 7) << 4;

    __shared__ unsigned short Kls[64 * 64];
    __shared__ unsigned short Vls[64 * 64];
    __shared__ unsigned short Pls[64 * 64];
    __shared__ float gks[64];
    __shared__ float qbs[64];

    const size_t kgbase = (size_t)h * T_SEQ * HD;
    const size_t vgbase = (size_t)h * HD * T_SEQ;

    const int qrow_a = q0 + 16 * w + lm;
    bf16x8 aq[2];
    aq[0] = *reinterpret_cast<const bf16x8*>(qb + (size_t)qrow_a * HID + h * HD + lg * 8);
    aq[1] = *reinterpret_cast<const bf16x8*>(qb + (size_t)qrow_a * HID + h * HD + 32 + lg * 8);
    float qn2 = 0.f;
    #pragma unroll
    for (int ks = 0; ks < 2; ++ks) {
        u16x8 uv = *reinterpret_cast<const u16x8*>(&aq[ks]);
        #pragma unroll
        for (int j = 0; j < 8; ++j) { float x = bf2f(uv[j]); qn2 += x * x; }
    }
    qn2 += __shfl_xor(qn2, 16);
    qn2 += __shfl_xor(qn2, 32);
    if (lg == 0) qbs[16 * w + lm] = sqrtf(qn2) * knmax[h];

    float gq_r[4];
    #pragma unroll
    for (int reg = 0; reg < 4; ++reg)
        gq_r[reg] = gc[(q0 + 16 * w + lg * 4 + reg) * NH + h];

    float mrun[4], lrun[4];
    #pragma unroll
    for (int reg = 0; reg < 4; ++reg) { mrun[reg] = -1e30f; lrun[reg] = 0.f; }
    f32x4 acc[4];
    #pragma unroll
    for (int db = 0; db < 4; ++db) acc[db] = (f32x4){0.f, 0.f, 0.f, 0.f};

    const int stp = dir ? 1 : -1;
    for (int kt = qt; kt >= 0 && kt < NT; kt += stp) {
        const int k0 = kt * 64;

        #pragma unroll
        for (int j = 0; j < 2; ++j) {
            const int idxb = j * 4096 + tid * 16;
            const int row  = idxb >> 7;
            const int kbyt = idxb & 127;
            const int scol = (kbyt ^ ((row & 7) << 4)) >> 1;
            const int ldsh = (j * 4096 + w * 1024) >> 1;
            __builtin_amdgcn_global_load_lds(
                GPTR(kg + kgbase + (size_t)(k0 + row) * HD + scol),
                SPTR(Kls + ldsh), 16, 0, 0);
            __builtin_amdgcn_global_load_lds(
                GPTR(vg + vgbase + (size_t)row * T_SEQ + k0 + scol),
                SPTR(Vls + ldsh), 16, 0, 0);
        }
        if (w == 0)
            __builtin_amdgcn_global_load_lds(
                GPTR(gc + (size_t)(k0 + l) * NH + h), SPTR(gks), 4, 0, 0);
        __syncthreads();

        f32x4 s[4];
        #pragma unroll
        for (int cb = 0; cb < 4; ++cb) {
            bf16x8 b0 = *reinterpret_cast<const bf16x8*>(
                (char*)Kls + (cb * 16 + lm) * 128 + ((lg * 16) ^ swz));
            bf16x8 b1 = *reinterpret_cast<const bf16x8*>(
                (char*)Kls + (cb * 16 + lm) * 128 + ((64 + lg * 16) ^ swz));
            f32x4 z = (f32x4){0.f, 0.f, 0.f, 0.f};
            z = __builtin_amdgcn_mfma_f32_16x16x32_bf16(aq[0], b0, z, 0, 0, 0);
            s[cb] = __builtin_amdgcn_mfma_f32_16x16x32_bf16(aq[1], b1, z, 0, 0, 0);
        }

        float gk_c[4];
        #pragma unroll
        for (int cb = 0; cb < 4; ++cb) gk_c[cb] = gks[cb * 16 + lm];
        float sv[4][4];
        const bool diag = (kt == qt);
        #pragma unroll
        for (int cb = 0; cb < 4; ++cb)
            #pragma unroll
            for (int reg = 0; reg < 4; ++reg) {
                float x = s[cb][reg] + gq_r[reg] - gk_c[cb];
                if (diag) {
                    const int c_loc = cb * 16 + lm;
                    const int r_loc = 16 * w + lg * 4 + reg;
                    const bool valid = dir ? (c_loc >= r_loc) : (c_loc <= r_loc);
                    x = valid ? x : -1e30f;
                }
                sv[cb][reg] = x;
            }

        float corr[4], mnew[4];
        #pragma unroll
        for (int reg = 0; reg < 4; ++reg) {
            float rm = fmaxf(fmaxf(sv[0][reg], sv[1][reg]), fmaxf(sv[2][reg], sv[3][reg]));
            rm = fmaxf(rm, __shfl_xor(rm, 1));
            rm = fmaxf(rm, __shfl_xor(rm, 2));
            rm = fmaxf(rm, __shfl_xor(rm, 4));
            rm = fmaxf(rm, __shfl_xor(rm, 8));
            mnew[reg] = fmaxf(mrun[reg], rm);
            corr[reg] = __expf(mrun[reg] - mnew[reg]);
            mrun[reg] = mnew[reg];
        }
        float psum[4] = {0.f, 0.f, 0.f, 0.f};
        #pragma unroll
        for (int cb = 0; cb < 4; ++cb)
            #pragma unroll
            for (int reg = 0; reg < 4; ++reg) {
                const float p = __expf(sv[cb][reg] - mnew[reg]);
                psum[reg] += p;
                const int r_loc = 16 * w + lg * 4 + reg;
                *reinterpret_cast<unsigned short*>(
                    (char*)Pls + r_loc * 128 + ((cb * 32 + lm * 2) ^ ((r_loc & 7) << 4))) = f2bf(p);
            }
        #pragma unroll
        for (int reg = 0; reg < 4; ++reg) {
            float ps = psum[reg];
            ps += __shfl_xor(ps, 1);
            ps += __shfl_xor(ps, 2);
            ps += __shfl_xor(ps, 4);
            ps += __shfl_xor(ps, 8);
            lrun[reg] = lrun[reg] * corr[reg] + ps;
        }
        #pragma unroll
        for (int db = 0; db < 4; ++db)
            #pragma unroll
            for (int reg = 0; reg < 4; ++reg) acc[db][reg] *= corr[reg];

        bf16x8 ap[2];
        #pragma unroll
        for (int ks = 0; ks < 2; ++ks)
            ap[ks] = *reinterpret_cast<const bf16x8*>(
                (char*)Pls + (16 * w + lm) * 128 + ((ks * 64 + lg * 16) ^ swz));
        #pragma unroll
        for (int db = 0; db < 4; ++db) {
            bf16x8 bv0 = *reinterpret_cast<const bf16x8*>(
                (char*)Vls + (db * 16 + lm) * 128 + ((lg * 16) ^ swz));
            bf16x8 bv1 = *reinterpret_cast<const bf16x8*>(
                (char*)Vls + (db * 16 + lm) * 128 + ((64 + lg * 16) ^ swz));
            acc[db] = __builtin_amdgcn_mfma_f32_16x16x32_bf16(ap[0], bv0, acc[db], 0, 0, 0);
            acc[db] = __builtin_amdgcn_mfma_f32_16x16x32_bf16(ap[1], bv1, acc[db], 0, 0, 0);
        }

        const int nkt = kt + stp;
        if (nkt >= 0 && nkt < NT) {
            const float gkedge = dir ? gc[(nkt * 64) * NH + h]
                                     : gc[(nkt * 64 + 63) * NH + h];
            int pred = 0;
            #pragma unroll
            for (int reg = 0; reg < 4; ++reg) {
                const float qbv = qbs[16 * w + lg * 4 + reg];
                pred |= (qbv + gq_r[reg] - gkedge) >= (mrun[reg] - 15.f);
            }
            if (!__syncthreads_or(pred)) break;
        }
    }

    float inv[4];
    #pragma unroll
    for (int reg = 0; reg < 4; ++reg) inv[reg] = 1.f / lrun[reg];
    #pragma unroll
    for (int db = 0; db < 4; ++db)
        #pragma unroll
        for (int reg = 0; reg < 4; ++reg) {
            const int row = q0 + 16 * w + lg * 4 + reg;
            const int col = db * 16 + lm;
            ocat[(size_t)row * (2 * HID) + dir * HID + h * HD + col] =
                f2bf(acc[db][reg] * inv[reg]);
        }
}

// ---------------- launch ----------------
extern "C" void kernel_launch(void* const* d_in, const int* in_sizes, int n_in,
                              void* d_out, int out_size, void* d_ws, size_t ws_size,
                              hipStream_t stream)
{
    (void)in_sizes; (void)n_in; (void)out_size; (void)ws_size;
    const float* hs = (const float*)d_in[0];
    const float* Wq = (const float*)d_in[1];
    const float* Wk = (const float*)d_in[2];
    const float* Wv = (const float*)d_in[3];
    const float* Wf = (const float*)d_in[4];
    const float* bf = (const float*)d_in[5];
    const float* Wo = (const float*)d_in[6];
    float* out = (float*)d_out;

    float* ws    = (float*)d_ws;
    float* f     = ws;
    float* gcf   = f   + (size_t)T_SEQ * NH;
    float* gcb   = gcf + (size_t)T_SEQ * NH;
    float* knmax = gcb + (size_t)T_SEQ * NH;
    unsigned short* hsb  = (unsigned short*)(knmax + 64);
    unsigned short* wqb  = hsb + (size_t)T_SEQ * HID;
    unsigned short* wkb  = wqb + (size_t)HID * HID;
    unsigned short* wvb  = wkb + (size_t)HID * HID;
    unsigned short* wob  = wvb + (size_t)HID * HID;
    unsigned short* qb   = wob + (size_t)HID * 2 * HID;
    unsigned short* kb   = qb  + (size_t)T_SEQ * HID;
    unsigned short* vt   = kb  + (size_t)T_SEQ * HID;
    unsigned short* ocat = vt  + (size_t)T_SEQ * HID;

    // L1: conversions + fproj fused
    prep1<<<dim3(2048, 6), 256, 0, stream>>>(
        hs, Wq, Wk, Wv, Wo, Wf, bf, hsb, wqb, wkb, wvb, wob, f);

    // L2: qkv projections (128x64 tile, dbuf) -> attention-native layouts
    gemm_mfma_bt<128, 64, 0><<<dim3(HID / 64, T_SEQ / 128, 3), 256, 0, stream>>>(
        hsb, wqb, wkb, wvb, nullptr, qb, kb, vt, T_SEQ, HID, HID);

    // L3: cumsum + knorms fused
    prep2<<<48, 256, 0, stream>>>(f, gcf, gcb, kb, knmax);

    // L4: attention, both dirs
    attn_flash<<<dim3(NT, NH, 2), 256, 0, stream>>>(qb, kb, vt, gcf, gcb, knmax, ocat);

    // L5: out = ocat @ Wo^T (64x64 tile, dbuf)
    gemm_mfma_bt<64, 64, 1><<<dim3(HID / 64, T_SEQ / 64, 1), 256, 0, stream>>>(
        ocat, wob, nullptr, nullptr, out, nullptr, nullptr, nullptr,
        T_SEQ, HID, 2 * HID);
}